// Round 10
// baseline (2288.715 us; speedup 1.0000x reference)
//
#include <hip/hip_runtime.h>
#include <hip/hip_cooperative_groups.h>
#include <math.h>

namespace cg = cooperative_groups;

#define TLEN 256
#define BATCH 4
#define DMODEL 768
#define DINNER 1536
#define NSTATE 16
#define DTRANK 48
#define NLAYER 4
#define NTOK 1024

#define S_IP 2359296
#define S_OP 1179648
#define S_XP2 196608            /* 128 x 1536 zero-padded */
#define S_DT 98304              /* 1536 x 64 zero-padded  */
#define WL (S_IP + S_OP + S_XP2 + S_DT)   /* 3,833,856 elems per layer */

#define GRID 256
#define NTHR 512

typedef __bf16 bf16x8 __attribute__((ext_vector_type(8)));
typedef float f32x4 __attribute__((ext_vector_type(4)));

__device__ inline unsigned short f2b(float f) {
    union { float f; unsigned u; } v;
    v.f = f;
    unsigned r = (v.u + 0x7fffu + ((v.u >> 16) & 1u)) >> 16;  // RNE
    return (unsigned short)r;
}
__device__ inline float b2f(unsigned short u) {
    union { unsigned u; float f; } v;
    v.u = ((unsigned)u) << 16;
    return v.f;
}
__device__ inline void gload16(const void* g, void* l) {
    __builtin_amdgcn_global_load_lds(
        (const __attribute__((address_space(1))) void*)g,
        (__attribute__((address_space(3))) void*)l, 16, 0, 0);
}
// 16-lane sum via DPP (quad xor1, xor2, row_ror 4, 8) — no DS ops.
__device__ inline float red16(float p) {
    p += __int_as_float(__builtin_amdgcn_update_dpp(0, __float_as_int(p), 0xB1, 0xf, 0xf, true));
    p += __int_as_float(__builtin_amdgcn_update_dpp(0, __float_as_int(p), 0x4E, 0xf, 0xf, true));
    p += __int_as_float(__builtin_amdgcn_update_dpp(0, __float_as_int(p), 0x124, 0xf, 0xf, true));
    p += __int_as_float(__builtin_amdgcn_update_dpp(0, __float_as_int(p), 0x128, 0xf, 0xf, true));
    return p;
}

struct SM {
    union {
        struct { unsigned short Ab[2][64 * 64]; unsigned short Bb[2][128 * 64]; } g;  // 48 KB
        struct { unsigned short tile[2][4][256]; } c;                                 // 4 KB
        struct { float yl[4][260], cum[4][260];
                 float hL[8][4][16], Pb[8][4][16], Hin[8][4][16]; } s;                // ~14.5 KB
        struct { float red[2][4], scale[2]; } r;
    };
};

// ---- 512-thread GEMM tile worker: D[64 rows][128 cols] = A[64,K] x B[128,K]^T ----
// MODE 0: ob = xzT bf16 [3072][1024]               (in_proj, rows=e cols=tok)
// MODE 1: ob = xdblb bf16 [1024][64] (rows<64); o2 = xdblT f32 rows 48..79  (x_proj)
// MODE 2: ob = dtT bf16, softplus(v + bias[row])   (dt_proj)
// MODE 3: of = x f32 accumulate, ob = xb mirror    (out_proj, rows=tok cols=d)
template <int MODE>
__device__ void gemm_tile(SM* sm, int tid,
                          const unsigned short* A, int lda,
                          const unsigned short* B, int ldb,
                          int K, int bm, int bn, const float* bias,
                          float* of, unsigned short* ob, float* o2) {
    int lane = tid & 63;
    int wave = tid >> 6;
    int wm = (wave >> 2) * 32;        // 0,32
    int wn = (wave & 3) * 32;         // 0,32,64,96
    int fr = lane & 15;
    int fq = lane >> 4;
    int fk = fq * 8;
    int sr = tid >> 3;                // 0..63
    int sc = (tid & 7) * 8;           // 0..56

    f32x4 acc[2][2] = {};

    auto stage = [&](int s, int k0) {
        gload16(A + (size_t)(bm + sr) * lda + k0 + sc, &sm->g.Ab[s][sr * 64 + sc]);
        gload16(B + (size_t)(bn + sr) * ldb + k0 + sc, &sm->g.Bb[s][sr * 64 + sc]);
        gload16(B + (size_t)(bn + 64 + sr) * ldb + k0 + sc, &sm->g.Bb[s][(64 + sr) * 64 + sc]);
    };

    int nk = K >> 6;
    stage(0, 0);
    asm volatile("s_waitcnt vmcnt(0)" ::: "memory");
    __builtin_amdgcn_s_barrier();

    for (int t = 0; t < nk; ++t) {
        int cur = t & 1;
        if (t + 1 < nk) stage(cur ^ 1, (t + 1) * 64);
#pragma unroll
        for (int ks = 0; ks < 2; ++ks) {
            int kk = ks * 32 + fk;
            bf16x8 af[2], bf[2];
#pragma unroll
            for (int i = 0; i < 2; ++i)
                af[i] = *(const bf16x8*)&sm->g.Ab[cur][(wm + i * 16 + fr) * 64 + kk];
#pragma unroll
            for (int j = 0; j < 2; ++j)
                bf[j] = *(const bf16x8*)&sm->g.Bb[cur][(wn + j * 16 + fr) * 64 + kk];
#pragma unroll
            for (int i = 0; i < 2; ++i)
#pragma unroll
                for (int j = 0; j < 2; ++j)
                    acc[i][j] = __builtin_amdgcn_mfma_f32_16x16x32_bf16(
                        af[i], bf[j], acc[i][j], 0, 0, 0);
        }
        asm volatile("s_waitcnt vmcnt(0)" ::: "memory");
        __builtin_amdgcn_s_barrier();
    }

#pragma unroll
    for (int i = 0; i < 2; ++i) {
#pragma unroll
        for (int j = 0; j < 2; ++j) {
            int lc = wn + j * 16 + fr;          // 0..127
#pragma unroll
            for (int q = 0; q < 4; ++q) {
                int lr = wm + i * 16 + fq * 4 + q;   // 0..63
                float v = acc[i][j][q];
                if (MODE == 0) {
                    ob[(size_t)(bm + lr) * NTOK + bn + lc] = f2b(v);
                } else if (MODE == 1) {
                    int f = bm + lr;
                    if (f < 64) ob[(size_t)(bn + lc) * 64 + f] = f2b(v);
                    if (f >= DTRANK && f < 80) o2[(size_t)f * NTOK + bn + lc] = v;
                } else if (MODE == 2) {
                    float s = v + bias[bm + lr];
                    s = (s > 0.f) ? s + log1pf(__expf(-s)) : log1pf(__expf(s));
                    ob[(size_t)(bm + lr) * NTOK + bn + lc] = f2b(s);
                } else {
                    size_t idx = (size_t)(bm + lr) * DMODEL + bn + lc;
                    float nv = of[idx] + v;
                    of[idx] = nv;
                    ob[idx] = f2b(nv);
                }
            }
        }
    }
}

// ---- scan unit: 512 threads = 8 chunks x (4 chains x 16 states) over 256 steps ----
__device__ void scan_unit(SM* sm, int tid, int dgrp, int b,
                          const unsigned short* dtT, const unsigned short* xzT,
                          const float* xdblT, const float* cw_l, const float* cb_l,
                          const float* Alog_l, const float* Dsk_l,
                          unsigned short* ybb) {
    int c = tid >> 6;
    int lane = tid & 63;
    int ch = lane >> 4;
    int n = lane & 15;
    int d = dgrp * 4 + ch;
    int tl0 = c * 32;

    float a = -__expf(Alog_l[(size_t)d * NSTATE + n]);
    float Dv = Dsk_l[d];
    float w0 = cw_l[d * 4 + 0], w1 = cw_l[d * 4 + 1], w2 = cw_l[d * 4 + 2], w3 = cw_l[d * 4 + 3];
    float cbv = cb_l[d];
    const unsigned short* dtp = dtT + (size_t)d * NTOK + b * TLEN + tl0;
    const unsigned short* xzp = xzT + (size_t)d * NTOK + b * TLEN + tl0;
    const float* Bp = xdblT + (size_t)(DTRANK + n) * NTOK + b * TLEN + tl0;
    const float* Cp = xdblT + (size_t)(DTRANK + NSTATE + n) * NTOK + b * TLEN + tl0;

    float hm3 = 0.f, hm2 = 0.f, hm1 = 0.f;
    if (tl0 > 0) {
        ushort4 pv = *(const ushort4*)(xzp - 4);
        hm3 = b2f(pv.y); hm2 = b2f(pv.z); hm1 = b2f(pv.w);
    }

    float h = 0.f, cd = 0.f;
    for (int t8 = 0; t8 < 32; t8 += 8) {
        ushort4 dv0 = *(const ushort4*)(dtp + t8), dv1 = *(const ushort4*)(dtp + t8 + 4);
        ushort4 xv0 = *(const ushort4*)(xzp + t8), xv1 = *(const ushort4*)(xzp + t8 + 4);
        float4 B0 = *(const float4*)(Bp + t8), B1 = *(const float4*)(Bp + t8 + 4);
        float4 C0 = *(const float4*)(Cp + t8), C1 = *(const float4*)(Cp + t8 + 4);
        float dts[8] = {b2f(dv0.x), b2f(dv0.y), b2f(dv0.z), b2f(dv0.w),
                        b2f(dv1.x), b2f(dv1.y), b2f(dv1.z), b2f(dv1.w)};
        float xw[11] = {hm3, hm2, hm1,
                        b2f(xv0.x), b2f(xv0.y), b2f(xv0.z), b2f(xv0.w),
                        b2f(xv1.x), b2f(xv1.y), b2f(xv1.z), b2f(xv1.w)};
        float Bs[8] = {B0.x, B0.y, B0.z, B0.w, B1.x, B1.y, B1.z, B1.w};
        float Cs[8] = {C0.x, C0.y, C0.z, C0.w, C1.x, C1.y, C1.z, C1.w};
#pragma unroll
        for (int u = 0; u < 8; ++u) {
            float sv = cbv + w0 * xw[u] + w1 * xw[u + 1] + w2 * xw[u + 2] + w3 * xw[u + 3];
            float xi = sv / (1.f + __expf(-sv));
            float dtv = dts[u];
            cd += dtv;
            float dA = __expf(dtv * a);
            h = dA * h + (dtv * xi) * Bs[u];
            float p = red16(h * Cs[u]);
            if (n == 0) {
                sm->s.yl[ch][tl0 + t8 + u] = p + Dv * xi;
                sm->s.cum[ch][tl0 + t8 + u] = cd;
            }
        }
        hm3 = xw[8]; hm2 = xw[9]; hm1 = xw[10];
    }
    sm->s.hL[c][ch][n] = h;
    sm->s.Pb[c][ch][n] = __expf(a * cd);
    __syncthreads();
    if (c == 0) {
        float H = 0.f;
        sm->s.Hin[0][ch][n] = 0.f;
#pragma unroll
        for (int cc = 1; cc < 8; ++cc) {
            H = sm->s.Pb[cc - 1][ch][n] * H + sm->s.hL[cc - 1][ch][n];
            sm->s.Hin[cc][ch][n] = H;
        }
    }
    __syncthreads();
    float Hv = sm->s.Hin[c][ch][n];
    const unsigned short* zp = xzT + (size_t)(DINNER + d) * NTOK + b * TLEN + tl0;
    for (int t8 = 0; t8 < 32; t8 += 8) {
        float4 C0 = *(const float4*)(Cp + t8), C1 = *(const float4*)(Cp + t8 + 4);
        ushort4 zv0 = *(const ushort4*)(zp + t8), zv1 = *(const ushort4*)(zp + t8 + 4);
        float Cs[8] = {C0.x, C0.y, C0.z, C0.w, C1.x, C1.y, C1.z, C1.w};
        float zs[8] = {b2f(zv0.x), b2f(zv0.y), b2f(zv0.z), b2f(zv0.w),
                       b2f(zv1.x), b2f(zv1.y), b2f(zv1.z), b2f(zv1.w)};
#pragma unroll
        for (int u = 0; u < 8; ++u) {
            float cdt = sm->s.cum[ch][tl0 + t8 + u];
            float corr = red16(Cs[u] * __expf(a * cdt) * Hv);
            if (n == 0) {
                float y = sm->s.yl[ch][tl0 + t8 + u] + corr;
                float zz = zs[u];
                y *= zz / (1.f + __expf(-zz));
                sm->s.yl[ch][tl0 + t8 + u] = y;
            }
        }
    }
    __syncthreads();
    if (tid < 256) {
        int t = tid;
        ushort4 o;
        o.x = f2b(sm->s.yl[0][t]);
        o.y = f2b(sm->s.yl[1][t]);
        o.z = f2b(sm->s.yl[2][t]);
        o.w = f2b(sm->s.yl[3][t]);
        *(ushort4*)(ybb + (size_t)(b * TLEN + t) * DINNER + dgrp * 4) = o;
    }
}

// ---------------- the whole network, one cooperative kernel ----------------
__global__ __launch_bounds__(NTHR, 2) void mega_k(
    const int* __restrict__ ids, const float* __restrict__ emb, const float* __restrict__ pos,
    const float* __restrict__ ipw, const float* __restrict__ cw, const float* __restrict__ cb,
    const float* __restrict__ xpw, const float* __restrict__ dpw, const float* __restrict__ dpb,
    const float* __restrict__ Alog, const float* __restrict__ Dsk, const float* __restrict__ opw,
    const float* __restrict__ nw,
    unsigned short* w_all, float* x, unsigned short* xb, unsigned short* xzT,
    unsigned short* xib, float* xdblT, unsigned short* xdblb, unsigned short* dtT,
    unsigned short* ybb, float* out) {
    __shared__ SM sm;
    cg::grid_group grid = cg::this_grid();
    int tid = threadIdx.x;
    int bid = blockIdx.x;

    // ---- stage: prep (weight convert + embed), flat grid-stride ----
    {
        const int PUL = WL / 4;                   // per-layer units (4 elems each)
        const int WUNITS = PUL * NLAYER;
        const int EUNITS = NTOK * DMODEL / 4;
        const int TOT = WUNITS + EUNITS;
        for (int u = bid * NTHR + tid; u < TOT; u += GRID * NTHR) {
            if (u < WUNITS) {
                int l = u / PUL;
                int i4 = (u - l * PUL) * 4;
                unsigned short* wl = w_all + (size_t)l * WL;
                if (i4 < S_IP) {
                    float4 v = *(const float4*)(ipw + (size_t)l * S_IP + i4);
                    ushort4 o; o.x = f2b(v.x); o.y = f2b(v.y); o.z = f2b(v.z); o.w = f2b(v.w);
                    *(ushort4*)(wl + i4) = o;
                } else if (i4 < S_IP + S_OP) {
                    int i = i4 - S_IP;
                    float4 v = *(const float4*)(opw + (size_t)l * S_OP + i);
                    ushort4 o; o.x = f2b(v.x); o.y = f2b(v.y); o.z = f2b(v.z); o.w = f2b(v.w);
                    *(ushort4*)(wl + S_IP + i) = o;
                } else if (i4 < S_IP + S_OP + S_XP2) {
                    int i = i4 - S_IP - S_OP;
                    int r = i / 1536, k = i % 1536;
                    ushort4 o = {0, 0, 0, 0};
                    if (r < 80) {
                        float4 v = *(const float4*)(xpw + (size_t)l * (80 * 1536) + (size_t)r * 1536 + k);
                        o.x = f2b(v.x); o.y = f2b(v.y); o.z = f2b(v.z); o.w = f2b(v.w);
                    }
                    *(ushort4*)(wl + S_IP + S_OP + i) = o;
                } else {
                    int i = i4 - S_IP - S_OP - S_XP2;
                    int r = i >> 6, k = i & 63;
                    ushort4 o = {0, 0, 0, 0};
                    if (k < DTRANK) {
                        float4 v = *(const float4*)(dpw + (size_t)l * (DINNER * DTRANK) + (size_t)r * DTRANK + k);
                        o.x = f2b(v.x); o.y = f2b(v.y); o.z = f2b(v.z); o.w = f2b(v.w);
                    }
                    *(ushort4*)(wl + S_IP + S_OP + S_XP2 + i) = o;
                }
            } else {
                int idx = (u - WUNITS) * 4;
                int d = idx % DMODEL;
                int bt = idx / DMODEL;
                int t = bt % TLEN;
                float4 ev = *(const float4*)(emb + (size_t)ids[bt] * DMODEL + d);
                float4 pv = *(const float4*)(pos + t * DMODEL + d);
                float4 xv;
                xv.x = ev.x + pv.x; xv.y = ev.y + pv.y; xv.z = ev.z + pv.z; xv.w = ev.w + pv.w;
                *(float4*)(x + idx) = xv;
                ushort4 o;
                o.x = f2b(xv.x); o.y = f2b(xv.y); o.z = f2b(xv.z); o.w = f2b(xv.w);
                *(ushort4*)(xb + idx) = o;
            }
        }
    }
    grid.sync();

    for (int l = 0; l < NLAYER; ++l) {
        const unsigned short* w_ip = w_all + (size_t)l * WL;
        const unsigned short* w_op = w_ip + S_IP;
        const unsigned short* w_xp = w_op + S_OP;
        const unsigned short* w_dt = w_xp + S_XP2;
        const float* cw_l = cw + (size_t)l * DINNER * 4;
        const float* cb_l = cb + (size_t)l * DINNER;
        const float* dpb_l = dpb + (size_t)l * DINNER;
        const float* Alog_l = Alog + (size_t)l * DINNER * NSTATE;
        const float* Dsk_l = Dsk + (size_t)l * DINNER;

        // in_proj: 384 tiles (48 rows x 8 token-tiles)
        for (int t = bid; t < 384; t += GRID)
            gemm_tile<0>(&sm, tid, w_ip, DMODEL, xb, DMODEL, DMODEL,
                         (t >> 3) * 64, (t & 7) * 128, nullptr, nullptr, xzT, nullptr);
        grid.sync();

        // conv: 1536 vblocks of 256 threads, 2 teams/block x 3 iters
        {
            int team = tid >> 8;
            int t2 = tid & 255;
            int ch = t2 >> 6;
            int t0 = (t2 & 63) * 4;
            for (int i = 0; i < 3; ++i) {
                int vb = bid * 2 + team + i * 512;
                int bx = vb >> 2;
                int b = vb & 3;
                int d = bx * 4 + ch;
                const unsigned short* src = xzT + (size_t)d * NTOK + b * TLEN + t0;
                ushort4 cur = *(const ushort4*)src;
                ushort4 prev = {0, 0, 0, 0};
                if (t0 > 0) prev = *(const ushort4*)(src - 4);
                float w0 = cw_l[d * 4 + 0], w1 = cw_l[d * 4 + 1];
                float w2 = cw_l[d * 4 + 2], w3 = cw_l[d * 4 + 3];
                float bb = cb_l[d];
                float xw[8] = {b2f(prev.x), b2f(prev.y), b2f(prev.z), b2f(prev.w),
                               b2f(cur.x), b2f(cur.y), b2f(cur.z), b2f(cur.w)};
#pragma unroll
                for (int u = 0; u < 4; ++u) {
                    float s = bb + w0 * xw[u + 1] + w1 * xw[u + 2] + w2 * xw[u + 3] + w3 * xw[u + 4];
                    sm.c.tile[team][ch][t0 + u] = f2b(s / (1.f + __expf(-s)));
                }
                __syncthreads();
                ushort4 o;
                o.x = sm.c.tile[team][0][t2];
                o.y = sm.c.tile[team][1][t2];
                o.z = sm.c.tile[team][2][t2];
                o.w = sm.c.tile[team][3][t2];
                *(ushort4*)(xib + (size_t)(b * TLEN + t2) * DINNER + bx * 4) = o;
                __syncthreads();
            }
        }
        grid.sync();

        // x_proj: 16 tiles (2 feat-tiles x 8 token-tiles)
        for (int t = bid; t < 16; t += GRID)
            gemm_tile<1>(&sm, tid, w_xp, DINNER, xib, DINNER, DINNER,
                         (t >> 3) * 64, (t & 7) * 128, nullptr, nullptr, xdblb, xdblT);
        grid.sync();

        // dt_proj: 192 tiles (24 d-tiles x 8 token-tiles), K=64
        for (int t = bid; t < 192; t += GRID)
            gemm_tile<2>(&sm, tid, w_dt, 64, xdblb, 64, 64,
                         (t >> 3) * 64, (t & 7) * 128, dpb_l, nullptr, dtT, nullptr);
        grid.sync();

        // scan: 1536 units, 6 per block
        for (int i = 0; i < 6; ++i) {
            int unit = bid + i * GRID;
            scan_unit(&sm, tid, unit % 384, unit / 384,
                      dtT, xzT, xdblT, cw_l, cb_l, Alog_l, Dsk_l, ybb);
            __syncthreads();
        }
        grid.sync();

        // out_proj: 96 tiles (16 token-tiles x 6 d-tiles)
        for (int t = bid; t < 96; t += GRID)
            gemm_tile<3>(&sm, tid, ybb, DINNER, w_op, DINNER, DINNER,
                         (t / 6) * 64, (t % 6) * 128, nullptr, x, xb, nullptr);
        grid.sync();
    }

    // rmsnorm: 1024 rows, 2 teams/block x 2 iters
    {
        int team = tid >> 8;
        int t2 = tid & 255;
        for (int i = 0; i < 2; ++i) {
            int row = bid * 2 + team + i * 512;
            const float* xr = x + (size_t)row * DMODEL;
            float s = 0.f;
            for (int d = t2; d < DMODEL; d += 256) {
                float v = xr[d];
                s += v * v;
            }
#pragma unroll
            for (int off = 32; off >= 1; off >>= 1) s += __shfl_down(s, off);
            int wid2 = t2 >> 6;
            if ((t2 & 63) == 0) sm.r.red[team][wid2] = s;
            __syncthreads();
            if (t2 == 0) {
                float tot = sm.r.red[team][0] + sm.r.red[team][1] +
                            sm.r.red[team][2] + sm.r.red[team][3];
                sm.r.scale[team] = rsqrtf(tot / (float)DMODEL + 1e-5f);
            }
            __syncthreads();
            float sc = sm.r.scale[team];
            for (int d = t2; d < DMODEL; d += 256)
                out[(size_t)row * DMODEL + d] = xr[d] * sc * nw[d];
            __syncthreads();
        }
    }
}

extern "C" void kernel_launch(void* const* d_in, const int* in_sizes, int n_in,
                              void* d_out, int out_size, void* d_ws, size_t ws_size,
                              hipStream_t stream) {
    const int* ids = (const int*)d_in[0];
    const float* emb = (const float*)d_in[1];
    const float* pos = (const float*)d_in[2];
    const float* ipw = (const float*)d_in[3];
    const float* cw = (const float*)d_in[4];
    const float* cb = (const float*)d_in[5];
    const float* xpw = (const float*)d_in[6];
    const float* dpw = (const float*)d_in[7];
    const float* dpb = (const float*)d_in[8];
    const float* Alog = (const float*)d_in[9];
    const float* Dsk = (const float*)d_in[10];
    const float* opw = (const float*)d_in[11];
    const float* nw = (const float*)d_in[12];

    float* x = (float*)d_ws;                                // 786432 f32
    float* xdblT = x + 786432;                              // 81920 f32
    unsigned short* xb = (unsigned short*)(xdblT + 81920);  // 786432
    unsigned short* xzT = xb + 786432;                      // 3145728
    unsigned short* xib = xzT + 3145728;                    // 1572864
    unsigned short* dtT = xib + 1572864;                    // 1572864
    unsigned short* ybb = dtT + 1572864;                    // 1572864
    unsigned short* xdblb = ybb + 1572864;                  // 65536
    unsigned short* w_all = xdblb + 65536;                  // 4 * WL
    float* out = (float*)d_out;

    void* args[] = {
        (void*)&ids, (void*)&emb, (void*)&pos, (void*)&ipw, (void*)&cw, (void*)&cb,
        (void*)&xpw, (void*)&dpw, (void*)&dpb, (void*)&Alog, (void*)&Dsk, (void*)&opw,
        (void*)&nw,
        (void*)&w_all, (void*)&x, (void*)&xb, (void*)&xzT, (void*)&xib, (void*)&xdblT,
        (void*)&xdblb, (void*)&dtT, (void*)&ybb, (void*)&out};

    hipLaunchCooperativeKernel((void*)mega_k, dim3(GRID), dim3(NTHR), args, 0, stream);
}

// Round 11
// 521.557 us; speedup vs baseline: 4.3882x; 4.3882x over previous
//
#include <hip/hip_runtime.h>
#include <math.h>

#define TLEN 256
#define BATCH 4
#define DMODEL 768
#define DINNER 1536
#define NSTATE 16
#define DTRANK 48
#define NLAYER 4
#define NTOK 1024

#define S_IP 2359296
#define S_OP 1179648
#define S_XP2 196608            /* 128 x 1536 zero-padded */
#define S_DT 98304              /* 1536 x 64 zero-padded  */
#define WL (S_IP + S_OP + S_XP2 + S_DT)
#define NB_W (WL / 1024)
#define NB_WALL (NB_W * NLAYER)
#define NB_E (NTOK * DMODEL / 256)

typedef __bf16 bf16x8 __attribute__((ext_vector_type(8)));
typedef float f32x4 __attribute__((ext_vector_type(4)));

__device__ inline unsigned short f2b(float f) {
    union { float f; unsigned u; } v;
    v.f = f;
    unsigned r = (v.u + 0x7fffu + ((v.u >> 16) & 1u)) >> 16;  // RNE
    return (unsigned short)r;
}
__device__ inline float b2f(unsigned short u) {
    union { unsigned u; float f; } v;
    v.u = ((unsigned)u) << 16;
    return v.f;
}

__device__ inline void gload16(const void* g, void* l) {
    __builtin_amdgcn_global_load_lds(
        (const __attribute__((address_space(1))) void*)g,
        (__attribute__((address_space(3))) void*)l, 16, 0, 0);
}

// 16-lane sum via DPP (quad xor1, xor2, then row_ror 4, 8) — no DS ops.
__device__ inline float red16(float p) {
    p += __int_as_float(__builtin_amdgcn_update_dpp(0, __float_as_int(p), 0xB1, 0xf, 0xf, true));
    p += __int_as_float(__builtin_amdgcn_update_dpp(0, __float_as_int(p), 0x4E, 0xf, 0xf, true));
    p += __int_as_float(__builtin_amdgcn_update_dpp(0, __float_as_int(p), 0x124, 0xf, 0xf, true));
    p += __int_as_float(__builtin_amdgcn_update_dpp(0, __float_as_int(p), 0x128, 0xf, 0xf, true));
    return p;
}

// ---------------- prep: all-layer weight convert + embed, one dispatch ----------------
__global__ __launch_bounds__(256) void prep_k(const float* __restrict__ ipw,
                                              const float* __restrict__ opw,
                                              const float* __restrict__ xpw,
                                              const float* __restrict__ dpw,
                                              const int* __restrict__ ids,
                                              const float* __restrict__ emb,
                                              const float* __restrict__ pos,
                                              unsigned short* __restrict__ w_all,
                                              float* __restrict__ x,
                                              unsigned short* __restrict__ xb) {
    int bid = blockIdx.x;
    int tid = threadIdx.x;
    if (bid >= NB_WALL) {  // embed
        int idx = (bid - NB_WALL) * 256 + tid;
        int d = idx % DMODEL;
        int bt = idx / DMODEL;
        int t = bt % TLEN;
        float v = emb[(size_t)ids[bt] * DMODEL + d] + pos[t * DMODEL + d];
        x[idx] = v;
        xb[idx] = f2b(v);
        return;
    }
    int l = bid / NB_W;
    int i4 = ((bid % NB_W) * 256 + tid) * 4;
    unsigned short* wl = w_all + (size_t)l * WL;
    if (i4 < S_IP) {
        float4 v = *(const float4*)(ipw + (size_t)l * S_IP + i4);
        ushort4 o; o.x = f2b(v.x); o.y = f2b(v.y); o.z = f2b(v.z); o.w = f2b(v.w);
        *(ushort4*)(wl + i4) = o;
    } else if (i4 < S_IP + S_OP) {
        int i = i4 - S_IP;
        float4 v = *(const float4*)(opw + (size_t)l * S_OP + i);
        ushort4 o; o.x = f2b(v.x); o.y = f2b(v.y); o.z = f2b(v.z); o.w = f2b(v.w);
        *(ushort4*)(wl + S_IP + i) = o;
    } else if (i4 < S_IP + S_OP + S_XP2) {
        int i = i4 - S_IP - S_OP;
        int r = i / 1536, k = i % 1536;
        ushort4 o = {0, 0, 0, 0};
        if (r < 80) {
            float4 v = *(const float4*)(xpw + (size_t)l * (80 * 1536) + (size_t)r * 1536 + k);
            o.x = f2b(v.x); o.y = f2b(v.y); o.z = f2b(v.z); o.w = f2b(v.w);
        }
        *(ushort4*)(wl + S_IP + S_OP + i) = o;
    } else {
        int i = i4 - S_IP - S_OP - S_XP2;
        int r = i >> 6, k = i & 63;
        ushort4 o = {0, 0, 0, 0};
        if (k < DTRANK) {
            float4 v = *(const float4*)(dpw + (size_t)l * (DINNER * DTRANK) + (size_t)r * DTRANK + k);
            o.x = f2b(v.x); o.y = f2b(v.y); o.z = f2b(v.z); o.w = f2b(v.w);
        }
        *(ushort4*)(wl + S_IP + S_OP + S_XP2 + i) = o;
    }
}

// ---------------- in_proj GEMM: 128x128 tile (m97-style), bf16 out ----------------
// D[e][tok] = sum_k w_ip[e,k]*xb[tok,k]; out xzT bf16 [3072][1024]
__global__ __launch_bounds__(256) void ipgemm_k(const unsigned short* __restrict__ A,
                                                const unsigned short* __restrict__ B,
                                                unsigned short* __restrict__ o1) {
    __shared__ __align__(16) unsigned short Ab[2][128 * 64];
    __shared__ __align__(16) unsigned short Bb[2][128 * 64];

    int tid = threadIdx.x;
    int lane = tid & 63;
    int wave = tid >> 6;
    int wm = (wave >> 1) * 64;
    int wn = (wave & 1) * 64;
    int bm = blockIdx.x * 128;
    int bn = blockIdx.y * 128;
    int fr = lane & 15;
    int fq = lane >> 4;
    int fk = fq * 8;
    int srow = lane >> 3;
    int scol = (lane & 7) * 8;

    f32x4 acc[4][4] = {};

    auto stage = [&](int s, int k0) {
#pragma unroll
        for (int c = 0; c < 4; ++c) {
            int r = wave * 32 + c * 8;
            gload16(A + (size_t)(bm + r + srow) * DMODEL + k0 + scol, &Ab[s][r * 64]);
            gload16(B + (size_t)(bn + r + srow) * DMODEL + k0 + scol, &Bb[s][r * 64]);
        }
    };

    const int nk = DMODEL / 64;  // 12
    stage(0, 0);
    asm volatile("s_waitcnt vmcnt(0)" ::: "memory");
    __builtin_amdgcn_s_barrier();

    for (int t = 0; t < nk; ++t) {
        int cur = t & 1;
        if (t + 1 < nk) stage(cur ^ 1, (t + 1) * 64);
#pragma unroll
        for (int ks = 0; ks < 2; ++ks) {
            int kk = ks * 32 + fk;
            bf16x8 af[4], bfr[4];
#pragma unroll
            for (int i = 0; i < 4; ++i)
                af[i] = *(const bf16x8*)&Ab[cur][(wm + i * 16 + fr) * 64 + kk];
#pragma unroll
            for (int j = 0; j < 4; ++j)
                bfr[j] = *(const bf16x8*)&Bb[cur][(wn + j * 16 + fr) * 64 + kk];
#pragma unroll
            for (int i = 0; i < 4; ++i)
#pragma unroll
                for (int j = 0; j < 4; ++j)
                    acc[i][j] = __builtin_amdgcn_mfma_f32_16x16x32_bf16(
                        af[i], bfr[j], acc[i][j], 0, 0, 0);
        }
        asm volatile("s_waitcnt vmcnt(0)" ::: "memory");
        __builtin_amdgcn_s_barrier();
    }

#pragma unroll
    for (int i = 0; i < 4; ++i) {
#pragma unroll
        for (int j = 0; j < 4; ++j) {
            int lc = wn + j * 16 + fr;
#pragma unroll
            for (int q = 0; q < 4; ++q) {
                int lr = wm + i * 16 + fq * 4 + q;
                o1[(size_t)(bm + lr) * NTOK + bn + lc] = f2b(acc[i][j][q]);
            }
        }
    }
}

// ---------------- bf16 MFMA GEMM, 2-phase LDS double-buffer, BM=64 ----------------
// MODE 1: o0 = xdblT f32 rows 48..79 only; o1 = xdblb bf16 [1024][64]   (x_proj)
// MODE 2: o1 = dtT bf16 [1536][1024], softplus(v + bias[row])           (dt_proj)
// MODE 3: o0 = x [1024][768] f32 accumulate, o1 = xb bf16 mirror        (out_proj)
template <int MODE>
__global__ __launch_bounds__(256) void mgemm_k(const unsigned short* __restrict__ A, int lda,
                                               const unsigned short* __restrict__ B, int ldb,
                                               int K,
                                               const float* __restrict__ bias,
                                               float* __restrict__ o0,
                                               unsigned short* __restrict__ o1) {
    __shared__ __align__(16) unsigned short Ab[2][64 * 64];
    __shared__ __align__(16) unsigned short Bb[2][64 * 64];
    __shared__ float Tt[(MODE == 1) ? 64 * 64 : 1];

    int tid = threadIdx.x;
    int lane = tid & 63;
    int wave = tid >> 6;
    int wm = (wave >> 1) * 32;
    int wn = (wave & 1) * 32;
    int bm = blockIdx.x * 64;
    int bn = blockIdx.y * 64;
    int fr = lane & 15;
    int fq = lane >> 4;
    int fk = fq * 8;
    int srow = lane >> 3;
    int scol = (lane & 7) * 8;

    f32x4 acc[2][2] = {};

    auto stage = [&](int s, int k0) {
#pragma unroll
        for (int c = 0; c < 2; ++c) {
            int r = wave * 16 + c * 8;
            gload16(A + (size_t)(bm + r + srow) * lda + k0 + scol, &Ab[s][r * 64]);
            gload16(B + (size_t)(bn + r + srow) * ldb + k0 + scol, &Bb[s][r * 64]);
        }
    };

    int nk = K >> 6;
    stage(0, 0);
    asm volatile("s_waitcnt vmcnt(0)" ::: "memory");
    __builtin_amdgcn_s_barrier();

    for (int t = 0; t < nk; ++t) {
        int cur = t & 1;
        if (t + 1 < nk) stage(cur ^ 1, (t + 1) * 64);
#pragma unroll
        for (int ks = 0; ks < 2; ++ks) {
            int kk = ks * 32 + fk;
            bf16x8 af[2], bfr[2];
#pragma unroll
            for (int i = 0; i < 2; ++i)
                af[i] = *(const bf16x8*)&Ab[cur][(wm + i * 16 + fr) * 64 + kk];
#pragma unroll
            for (int j = 0; j < 2; ++j)
                bfr[j] = *(const bf16x8*)&Bb[cur][(wn + j * 16 + fr) * 64 + kk];
#pragma unroll
            for (int i = 0; i < 2; ++i)
#pragma unroll
                for (int j = 0; j < 2; ++j)
                    acc[i][j] = __builtin_amdgcn_mfma_f32_16x16x32_bf16(
                        af[i], bfr[j], acc[i][j], 0, 0, 0);
        }
        asm volatile("s_waitcnt vmcnt(0)" ::: "memory");
        __builtin_amdgcn_s_barrier();
    }

#pragma unroll
    for (int i = 0; i < 2; ++i) {
#pragma unroll
        for (int j = 0; j < 2; ++j) {
            int lc = wn + j * 16 + fr;
#pragma unroll
            for (int q = 0; q < 4; ++q) {
                int lr = wm + i * 16 + fq * 4 + q;
                float v = acc[i][j][q];
                if (MODE == 1) {
                    int f = bm + lr;
                    if (f >= DTRANK && f < 80) o0[(size_t)f * NTOK + bn + lc] = v;
                    Tt[lc * 64 + lr] = v;
                } else if (MODE == 2) {
                    float s = v + bias[bm + lr];
                    s = (s > 0.f) ? s + log1pf(__expf(-s)) : log1pf(__expf(s));
                    o1[(size_t)(bm + lr) * NTOK + bn + lc] = f2b(s);
                } else if (MODE == 3) {
                    size_t idx = (size_t)(bm + lr) * DMODEL + bn + lc;
                    float nv = o0[idx] + v;
                    o0[idx] = nv;
                    o1[idx] = f2b(nv);
                }
            }
        }
    }
    if (MODE == 1) {
        __syncthreads();
        if (bm == 0) {   // rows 0..63 = dt-feats (48) + B (zero-weighted in dt GEMM)
            int tok = tid >> 2;
            int fb = (tid & 3) * 16;
#pragma unroll
            for (int vv = 0; vv < 4; ++vv) {
                int f0 = fb + vv * 4;
                ushort4 o;
                o.x = f2b(Tt[tok * 64 + f0 + 0]);
                o.y = f2b(Tt[tok * 64 + f0 + 1]);
                o.z = f2b(Tt[tok * 64 + f0 + 2]);
                o.w = f2b(Tt[tok * 64 + f0 + 3]);
                *(ushort4*)(o1 + (size_t)(bn + tok) * 64 + f0) = o;
            }
        }
    }
}

// ---------------- causal dwconv(K=4) + bias + SiLU, bf16 in/out ----------------
__global__ __launch_bounds__(256) void conv_k(const unsigned short* __restrict__ xzT,
                                              const float* __restrict__ cw,
                                              const float* __restrict__ cb,
                                              unsigned short* __restrict__ xib) {
    __shared__ unsigned short tile[4][256];
    int tid = threadIdx.x;
    int ch = tid >> 6;
    int d = blockIdx.x * 4 + ch;
    int b = blockIdx.y;
    int t0 = (tid & 63) * 4;
    const unsigned short* src = xzT + (size_t)d * NTOK + b * TLEN + t0;
    ushort4 cur = *(const ushort4*)src;
    ushort4 prev = {0, 0, 0, 0};
    if (t0 > 0) prev = *(const ushort4*)(src - 4);
    float w0 = cw[d * 4 + 0], w1 = cw[d * 4 + 1], w2 = cw[d * 4 + 2], w3 = cw[d * 4 + 3];
    float bb = cb[d];
    float xw[8] = {b2f(prev.x), b2f(prev.y), b2f(prev.z), b2f(prev.w),
                   b2f(cur.x), b2f(cur.y), b2f(cur.z), b2f(cur.w)};
#pragma unroll
    for (int u = 0; u < 4; ++u) {
        float s = bb + w0 * xw[u + 1] + w1 * xw[u + 2] + w2 * xw[u + 3] + w3 * xw[u + 4];
        float v = s / (1.f + __expf(-s));
        tile[ch][t0 + u] = f2b(v);
    }
    __syncthreads();
    int t = tid;
    ushort4 o;
    o.x = tile[0][t]; o.y = tile[1][t]; o.z = tile[2][t]; o.w = tile[3][t];
    *(ushort4*)(xib + (size_t)(b * TLEN + t) * DINNER + blockIdx.x * 4) = o;
}

// ---------------- selective scan, 8 waves x 32-step chunks, DPP reduce, inline conv ----
__global__ __launch_bounds__(512) void scan_k(const unsigned short* __restrict__ dtT,
                                              const unsigned short* __restrict__ xzT,
                                              const float* __restrict__ xdblT,
                                              const float* __restrict__ cw,
                                              const float* __restrict__ cb,
                                              const float* __restrict__ Alog,
                                              const float* __restrict__ Dsk,
                                              unsigned short* __restrict__ ybb) {
    __shared__ float yl[4][260];
    __shared__ float cum[4][260];
    __shared__ float hL[8][4][16];
    __shared__ float Pb[8][4][16];
    __shared__ float Hin[8][4][16];

    int tid = threadIdx.x;
    int c = tid >> 6;
    int lane = tid & 63;
    int ch = lane >> 4;
    int n = lane & 15;
    int d = blockIdx.x * 4 + ch;
    int b = blockIdx.y;
    int tl0 = c * 32;

    float a = -__expf(Alog[(size_t)d * NSTATE + n]);
    float Dv = Dsk[d];
    float w0 = cw[d * 4 + 0], w1 = cw[d * 4 + 1], w2 = cw[d * 4 + 2], w3 = cw[d * 4 + 3];
    float cbv = cb[d];
    const unsigned short* dtp = dtT + (size_t)d * NTOK + b * TLEN + tl0;
    const unsigned short* xzp = xzT + (size_t)d * NTOK + b * TLEN + tl0;
    const float* Bp = xdblT + (size_t)(DTRANK + n) * NTOK + b * TLEN + tl0;
    const float* Cp = xdblT + (size_t)(DTRANK + NSTATE + n) * NTOK + b * TLEN + tl0;

    float hm3 = 0.f, hm2 = 0.f, hm1 = 0.f;
    if (tl0 > 0) {
        ushort4 pv = *(const ushort4*)(xzp - 4);
        hm3 = b2f(pv.y); hm2 = b2f(pv.z); hm1 = b2f(pv.w);
    }

    float h = 0.f, cd = 0.f;
    for (int t8 = 0; t8 < 32; t8 += 8) {
        ushort4 dv0 = *(const ushort4*)(dtp + t8), dv1 = *(const ushort4*)(dtp + t8 + 4);
        ushort4 xv0 = *(const ushort4*)(xzp + t8), xv1 = *(const ushort4*)(xzp + t8 + 4);
        float4 B0 = *(const float4*)(Bp + t8), B1 = *(const float4*)(Bp + t8 + 4);
        float4 C0 = *(const float4*)(Cp + t8), C1 = *(const float4*)(Cp + t8 + 4);
        float dts[8] = {b2f(dv0.x), b2f(dv0.y), b2f(dv0.z), b2f(dv0.w),
                        b2f(dv1.x), b2f(dv1.y), b2f(dv1.z), b2f(dv1.w)};
        float xw[11] = {hm3, hm2, hm1,
                        b2f(xv0.x), b2f(xv0.y), b2f(xv0.z), b2f(xv0.w),
                        b2f(xv1.x), b2f(xv1.y), b2f(xv1.z), b2f(xv1.w)};
        float Bs[8] = {B0.x, B0.y, B0.z, B0.w, B1.x, B1.y, B1.z, B1.w};
        float Cs[8] = {C0.x, C0.y, C0.z, C0.w, C1.x, C1.y, C1.z, C1.w};
#pragma unroll
        for (int u = 0; u < 8; ++u) {
            float sv = cbv + w0 * xw[u] + w1 * xw[u + 1] + w2 * xw[u + 2] + w3 * xw[u + 3];
            float xi = sv / (1.f + __expf(-sv));
            float dtv = dts[u];
            cd += dtv;
            float dA = __expf(dtv * a);
            h = dA * h + (dtv * xi) * Bs[u];
            float p = red16(h * Cs[u]);
            if (n == 0) {
                yl[ch][tl0 + t8 + u] = p + Dv * xi;
                cum[ch][tl0 + t8 + u] = cd;
            }
        }
        hm3 = xw[8]; hm2 = xw[9]; hm1 = xw[10];
    }
    hL[c][ch][n] = h;
    Pb[c][ch][n] = __expf(a * cd);
    __syncthreads();
    if (c == 0) {
        float H = 0.f;
        Hin[0][ch][n] = 0.f;
#pragma unroll
        for (int cc = 1; cc < 8; ++cc) {
            H = Pb[cc - 1][ch][n] * H + hL[cc - 1][ch][n];
            Hin[cc][ch][n] = H;
        }
    }
    __syncthreads();
    float Hv = Hin[c][ch][n];
    const unsigned short* zp = xzT + (size_t)(DINNER + d) * NTOK + b * TLEN + tl0;
    for (int t8 = 0; t8 < 32; t8 += 8) {
        float4 C0 = *(const float4*)(Cp + t8), C1 = *(const float4*)(Cp + t8 + 4);
        ushort4 zv0 = *(const ushort4*)(zp + t8), zv1 = *(const ushort4*)(zp + t8 + 4);
        float Cs[8] = {C0.x, C0.y, C0.z, C0.w, C1.x, C1.y, C1.z, C1.w};
        float zs[8] = {b2f(zv0.x), b2f(zv0.y), b2f(zv0.z), b2f(zv0.w),
                       b2f(zv1.x), b2f(zv1.y), b2f(zv1.z), b2f(zv1.w)};
#pragma unroll
        for (int u = 0; u < 8; ++u) {
            float cdt = cum[ch][tl0 + t8 + u];
            float corr = red16(Cs[u] * __expf(a * cdt) * Hv);
            if (n == 0) {
                float y = yl[ch][tl0 + t8 + u] + corr;
                float zz = zs[u];
                y *= zz / (1.f + __expf(-zz));
                yl[ch][tl0 + t8 + u] = y;
            }
        }
    }
    __syncthreads();
    if (tid < 256) {
        int t = tid;
        ushort4 o;
        o.x = f2b(yl[0][t]);
        o.y = f2b(yl[1][t]);
        o.z = f2b(yl[2][t]);
        o.w = f2b(yl[3][t]);
        *(ushort4*)(ybb + (size_t)(b * TLEN + t) * DINNER + blockIdx.x * 4) = o;
    }
}

// ---------------- RMSNorm ----------------
__global__ __launch_bounds__(256) void rmsnorm_k(const float* __restrict__ x,
                                                 const float* __restrict__ nw,
                                                 float* __restrict__ out) {
    int row = blockIdx.x;
    const float* xr = x + (size_t)row * DMODEL;
    int tid = threadIdx.x;
    float s = 0.f;
    for (int d = tid; d < DMODEL; d += 256) {
        float v = xr[d];
        s += v * v;
    }
#pragma unroll
    for (int off = 32; off >= 1; off >>= 1) s += __shfl_down(s, off);
    __shared__ float red[4];
    __shared__ float scale;
    int wid = tid >> 6, lane = tid & 63;
    if (lane == 0) red[wid] = s;
    __syncthreads();
    if (tid == 0) {
        float tot = red[0] + red[1] + red[2] + red[3];
        scale = rsqrtf(tot / (float)DMODEL + 1e-5f);
    }
    __syncthreads();
    float sc = scale;
    for (int d = tid; d < DMODEL; d += 256)
        out[(size_t)row * DMODEL + d] = xr[d] * sc * nw[d];
}

extern "C" void kernel_launch(void* const* d_in, const int* in_sizes, int n_in,
                              void* d_out, int out_size, void* d_ws, size_t ws_size,
                              hipStream_t stream) {
    const int* ids = (const int*)d_in[0];
    const float* emb = (const float*)d_in[1];
    const float* pos = (const float*)d_in[2];
    const float* ipw = (const float*)d_in[3];
    const float* cw = (const float*)d_in[4];
    const float* cb = (const float*)d_in[5];
    const float* xpw = (const float*)d_in[6];
    const float* dpw = (const float*)d_in[7];
    const float* dpb = (const float*)d_in[8];
    const float* Alog = (const float*)d_in[9];
    const float* Dsk = (const float*)d_in[10];
    const float* opw = (const float*)d_in[11];
    const float* nw = (const float*)d_in[12];

    float* x = (float*)d_ws;                             // 786432 f32
    float* xdblT = x + 786432;                           // 81920 f32
    unsigned short* xb = (unsigned short*)(xdblT + 81920);  // 786432
    unsigned short* xzT = xb + 786432;                   // 3145728
    unsigned short* xib = xzT + 3145728;                 // 1572864
    unsigned short* dtT = xib + 1572864;                 // 1572864
    unsigned short* ybb = dtT + 1572864;                 // 1572864
    unsigned short* xdblb = ybb + 1572864;               // 65536
    unsigned short* w_all = xdblb + 65536;               // 4 * WL

    prep_k<<<NB_WALL + NB_E, 256, 0, stream>>>(ipw, opw, xpw, dpw, ids, emb, pos,
                                               w_all, x, xb);

    for (int l = 0; l < NLAYER; ++l) {
        const unsigned short* w_ip = w_all + (size_t)l * WL;
        const unsigned short* w_op = w_ip + S_IP;
        const unsigned short* w_xp = w_op + S_OP;
        const unsigned short* w_dt = w_xp + S_XP2;
        const float* cw_l = cw + (size_t)l * DINNER * 4;
        const float* cb_l = cb + (size_t)l * DINNER;
        const float* dpb_l = dpb + (size_t)l * DINNER;
        const float* Alog_l = Alog + (size_t)l * DINNER * NSTATE;
        const float* Dsk_l = Dsk + (size_t)l * DINNER;

        // in_proj: xzT bf16 [3072][1024], 128x128 tiles, 192 blocks
        ipgemm_k<<<dim3(3072 / 128, NTOK / 128), 256, 0, stream>>>(w_ip, xb, xzT);
        // conv + silu -> xib bf16
        conv_k<<<dim3(DINNER / 4, BATCH), 256, 0, stream>>>(xzT, cw_l, cb_l, xib);
        // x_proj: xdblT f32 rows 48..79 + xdblb bf16 [1024][64]
        mgemm_k<1><<<dim3(2, NTOK / 64), 256, 0, stream>>>(
            w_xp, DINNER, xib, DINNER, DINNER, nullptr, xdblT, xdblb);
        // dt_proj: dtT bf16 = softplus(. + dpb), K=64
        mgemm_k<2><<<dim3(DINNER / 64, NTOK / 64), 256, 0, stream>>>(
            w_dt, 64, xdblb, 64, 64, dpb_l, nullptr, dtT);
        // scan
        scan_k<<<dim3(DINNER / 4, BATCH), 512, 0, stream>>>(
            dtT, xzT, xdblT, cw_l, cb_l, Alog_l, Dsk_l, ybb);
        // out_proj: x += y @ opw^T, xb = bf16(x)
        mgemm_k<3><<<dim3(NTOK / 64, DMODEL / 64), 256, 0, stream>>>(
            ybb, DINNER, w_op, DINNER, DINNER, nullptr, x, xb);
    }

    rmsnorm_k<<<NTOK, 256, 0, stream>>>(x, nw, (float*)d_out);
}

// Round 12
// 511.907 us; speedup vs baseline: 4.4710x; 1.0189x over previous
//
#include <hip/hip_runtime.h>
#include <math.h>

#define TLEN 256
#define BATCH 4
#define DMODEL 768
#define DINNER 1536
#define NSTATE 16
#define DTRANK 48
#define NLAYER 4
#define NTOK 1024

#define S_IP 2359296
#define S_OP 1179648
#define S_XP2 196608            /* 128 x 1536 zero-padded */
#define WL (S_IP + S_OP + S_XP2)
#define NB_W (WL / 1024)
#define NB_WALL (NB_W * NLAYER)
#define NB_E (NTOK * DMODEL / 256)

typedef __bf16 bf16x8 __attribute__((ext_vector_type(8)));
typedef float f32x4 __attribute__((ext_vector_type(4)));

__device__ inline unsigned short f2b(float f) {
    union { float f; unsigned u; } v;
    v.f = f;
    unsigned r = (v.u + 0x7fffu + ((v.u >> 16) & 1u)) >> 16;  // RNE
    return (unsigned short)r;
}
__device__ inline float b2f(unsigned short u) {
    union { unsigned u; float f; } v;
    v.u = ((unsigned)u) << 16;
    return v.f;
}

__device__ inline void gload16(const void* g, void* l) {
    __builtin_amdgcn_global_load_lds(
        (const __attribute__((address_space(1))) void*)g,
        (__attribute__((address_space(3))) void*)l, 16, 0, 0);
}

// 16-lane sum via DPP (quad xor1, xor2, then row_ror 4, 8) — no DS ops.
__device__ inline float red16(float p) {
    p += __int_as_float(__builtin_amdgcn_update_dpp(0, __float_as_int(p), 0xB1, 0xf, 0xf, true));
    p += __int_as_float(__builtin_amdgcn_update_dpp(0, __float_as_int(p), 0x4E, 0xf, 0xf, true));
    p += __int_as_float(__builtin_amdgcn_update_dpp(0, __float_as_int(p), 0x124, 0xf, 0xf, true));
    p += __int_as_float(__builtin_amdgcn_update_dpp(0, __float_as_int(p), 0x128, 0xf, 0xf, true));
    return p;
}

// ---------------- prep: all-layer weight convert + embed, one dispatch ----------------
__global__ __launch_bounds__(256) void prep_k(const float* __restrict__ ipw,
                                              const float* __restrict__ opw,
                                              const float* __restrict__ xpw,
                                              const int* __restrict__ ids,
                                              const float* __restrict__ emb,
                                              const float* __restrict__ pos,
                                              unsigned short* __restrict__ w_all,
                                              float* __restrict__ x,
                                              unsigned short* __restrict__ xb) {
    int bid = blockIdx.x;
    int tid = threadIdx.x;
    if (bid >= NB_WALL) {  // embed
        int idx = (bid - NB_WALL) * 256 + tid;
        int d = idx % DMODEL;
        int bt = idx / DMODEL;
        int t = bt % TLEN;
        float v = emb[(size_t)ids[bt] * DMODEL + d] + pos[t * DMODEL + d];
        x[idx] = v;
        xb[idx] = f2b(v);
        return;
    }
    int l = bid / NB_W;
    int i4 = ((bid % NB_W) * 256 + tid) * 4;
    unsigned short* wl = w_all + (size_t)l * WL;
    if (i4 < S_IP) {
        float4 v = *(const float4*)(ipw + (size_t)l * S_IP + i4);
        ushort4 o; o.x = f2b(v.x); o.y = f2b(v.y); o.z = f2b(v.z); o.w = f2b(v.w);
        *(ushort4*)(wl + i4) = o;
    } else if (i4 < S_IP + S_OP) {
        int i = i4 - S_IP;
        float4 v = *(const float4*)(opw + (size_t)l * S_OP + i);
        ushort4 o; o.x = f2b(v.x); o.y = f2b(v.y); o.z = f2b(v.z); o.w = f2b(v.w);
        *(ushort4*)(wl + S_IP + i) = o;
    } else {
        int i = i4 - S_IP - S_OP;
        int r = i / 1536, k = i % 1536;
        ushort4 o = {0, 0, 0, 0};
        if (r < 80) {
            float4 v = *(const float4*)(xpw + (size_t)l * (80 * 1536) + (size_t)r * 1536 + k);
            o.x = f2b(v.x); o.y = f2b(v.y); o.z = f2b(v.z); o.w = f2b(v.w);
        }
        *(ushort4*)(wl + S_IP + S_OP + i) = o;
    }
}

// ---------------- in_proj GEMM: 128x128 tile, bf16 out ----------------
__global__ __launch_bounds__(256) void ipgemm_k(const unsigned short* __restrict__ A,
                                                const unsigned short* __restrict__ B,
                                                unsigned short* __restrict__ o1) {
    __shared__ __align__(16) unsigned short Ab[2][128 * 64];
    __shared__ __align__(16) unsigned short Bb[2][128 * 64];

    int tid = threadIdx.x;
    int lane = tid & 63;
    int wave = tid >> 6;
    int wm = (wave >> 1) * 64;
    int wn = (wave & 1) * 64;
    int bm = blockIdx.x * 128;
    int bn = blockIdx.y * 128;
    int fr = lane & 15;
    int fq = lane >> 4;
    int fk = fq * 8;
    int srow = lane >> 3;
    int scol = (lane & 7) * 8;

    f32x4 acc[4][4] = {};

    auto stage = [&](int s, int k0) {
#pragma unroll
        for (int c = 0; c < 4; ++c) {
            int r = wave * 32 + c * 8;
            gload16(A + (size_t)(bm + r + srow) * DMODEL + k0 + scol, &Ab[s][r * 64]);
            gload16(B + (size_t)(bn + r + srow) * DMODEL + k0 + scol, &Bb[s][r * 64]);
        }
    };

    const int nk = DMODEL / 64;  // 12
    stage(0, 0);
    asm volatile("s_waitcnt vmcnt(0)" ::: "memory");
    __builtin_amdgcn_s_barrier();

    for (int t = 0; t < nk; ++t) {
        int cur = t & 1;
        if (t + 1 < nk) stage(cur ^ 1, (t + 1) * 64);
#pragma unroll
        for (int ks = 0; ks < 2; ++ks) {
            int kk = ks * 32 + fk;
            bf16x8 af[4], bfr[4];
#pragma unroll
            for (int i = 0; i < 4; ++i)
                af[i] = *(const bf16x8*)&Ab[cur][(wm + i * 16 + fr) * 64 + kk];
#pragma unroll
            for (int j = 0; j < 4; ++j)
                bfr[j] = *(const bf16x8*)&Bb[cur][(wn + j * 16 + fr) * 64 + kk];
#pragma unroll
            for (int i = 0; i < 4; ++i)
#pragma unroll
                for (int j = 0; j < 4; ++j)
                    acc[i][j] = __builtin_amdgcn_mfma_f32_16x16x32_bf16(
                        af[i], bfr[j], acc[i][j], 0, 0, 0);
        }
        asm volatile("s_waitcnt vmcnt(0)" ::: "memory");
        __builtin_amdgcn_s_barrier();
    }

#pragma unroll
    for (int i = 0; i < 4; ++i) {
#pragma unroll
        for (int j = 0; j < 4; ++j) {
            int lc = wn + j * 16 + fr;
#pragma unroll
            for (int q = 0; q < 4; ++q) {
                int lr = wm + i * 16 + fq * 4 + q;
                o1[(size_t)(bm + lr) * NTOK + bn + lc] = f2b(acc[i][j][q]);
            }
        }
    }
}

// ---------------- bf16 MFMA GEMM, 2-phase LDS double-buffer, BM=64 ----------------
// MODE 1: o0 = xdblT f32 [80][1024], all rows < 80 transposed           (x_proj)
// MODE 3: o0 = x [1024][768] f32 accumulate, o1 = xb bf16 mirror        (out_proj)
template <int MODE>
__global__ __launch_bounds__(256) void mgemm_k(const unsigned short* __restrict__ A, int lda,
                                               const unsigned short* __restrict__ B, int ldb,
                                               int K,
                                               float* __restrict__ o0,
                                               unsigned short* __restrict__ o1) {
    __shared__ __align__(16) unsigned short Ab[2][64 * 64];
    __shared__ __align__(16) unsigned short Bb[2][64 * 64];

    int tid = threadIdx.x;
    int lane = tid & 63;
    int wave = tid >> 6;
    int wm = (wave >> 1) * 32;
    int wn = (wave & 1) * 32;
    int bm = blockIdx.x * 64;
    int bn = blockIdx.y * 64;
    int fr = lane & 15;
    int fq = lane >> 4;
    int fk = fq * 8;
    int srow = lane >> 3;
    int scol = (lane & 7) * 8;

    f32x4 acc[2][2] = {};

    auto stage = [&](int s, int k0) {
#pragma unroll
        for (int c = 0; c < 2; ++c) {
            int r = wave * 16 + c * 8;
            gload16(A + (size_t)(bm + r + srow) * lda + k0 + scol, &Ab[s][r * 64]);
            gload16(B + (size_t)(bn + r + srow) * ldb + k0 + scol, &Bb[s][r * 64]);
        }
    };

    int nk = K >> 6;
    stage(0, 0);
    asm volatile("s_waitcnt vmcnt(0)" ::: "memory");
    __builtin_amdgcn_s_barrier();

    for (int t = 0; t < nk; ++t) {
        int cur = t & 1;
        if (t + 1 < nk) stage(cur ^ 1, (t + 1) * 64);
#pragma unroll
        for (int ks = 0; ks < 2; ++ks) {
            int kk = ks * 32 + fk;
            bf16x8 af[2], bfr[2];
#pragma unroll
            for (int i = 0; i < 2; ++i)
                af[i] = *(const bf16x8*)&Ab[cur][(wm + i * 16 + fr) * 64 + kk];
#pragma unroll
            for (int j = 0; j < 2; ++j)
                bfr[j] = *(const bf16x8*)&Bb[cur][(wn + j * 16 + fr) * 64 + kk];
#pragma unroll
            for (int i = 0; i < 2; ++i)
#pragma unroll
                for (int j = 0; j < 2; ++j)
                    acc[i][j] = __builtin_amdgcn_mfma_f32_16x16x32_bf16(
                        af[i], bfr[j], acc[i][j], 0, 0, 0);
        }
        asm volatile("s_waitcnt vmcnt(0)" ::: "memory");
        __builtin_amdgcn_s_barrier();
    }

#pragma unroll
    for (int i = 0; i < 2; ++i) {
#pragma unroll
        for (int j = 0; j < 2; ++j) {
            int lc = wn + j * 16 + fr;
#pragma unroll
            for (int q = 0; q < 4; ++q) {
                int lr = wm + i * 16 + fq * 4 + q;
                float v = acc[i][j][q];
                if (MODE == 1) {
                    int f = bm + lr;
                    if (f < 80) o0[(size_t)f * NTOK + bn + lc] = v;
                } else {  // MODE 3: residual accumulate + bf16 mirror
                    size_t idx = (size_t)(bm + lr) * DMODEL + bn + lc;
                    float nv = o0[idx] + v;
                    o0[idx] = nv;
                    o1[idx] = f2b(nv);
                }
            }
        }
    }
}

// ---------------- causal dwconv(K=4) + bias + SiLU, bf16 in/out ----------------
__global__ __launch_bounds__(256) void conv_k(const unsigned short* __restrict__ xzT,
                                              const float* __restrict__ cw,
                                              const float* __restrict__ cb,
                                              unsigned short* __restrict__ xib) {
    __shared__ unsigned short tile[4][256];
    int tid = threadIdx.x;
    int ch = tid >> 6;
    int d = blockIdx.x * 4 + ch;
    int b = blockIdx.y;
    int t0 = (tid & 63) * 4;
    const unsigned short* src = xzT + (size_t)d * NTOK + b * TLEN + t0;
    ushort4 cur = *(const ushort4*)src;
    ushort4 prev = {0, 0, 0, 0};
    if (t0 > 0) prev = *(const ushort4*)(src - 4);
    float w0 = cw[d * 4 + 0], w1 = cw[d * 4 + 1], w2 = cw[d * 4 + 2], w3 = cw[d * 4 + 3];
    float bb = cb[d];
    float xw[8] = {b2f(prev.x), b2f(prev.y), b2f(prev.z), b2f(prev.w),
                   b2f(cur.x), b2f(cur.y), b2f(cur.z), b2f(cur.w)};
#pragma unroll
    for (int u = 0; u < 4; ++u) {
        float s = bb + w0 * xw[u + 1] + w1 * xw[u + 2] + w2 * xw[u + 3] + w3 * xw[u + 4];
        float v = s / (1.f + __expf(-s));
        tile[ch][t0 + u] = f2b(v);
    }
    __syncthreads();
    int t = tid;
    ushort4 o;
    o.x = tile[0][t]; o.y = tile[1][t]; o.z = tile[2][t]; o.w = tile[3][t];
    *(ushort4*)(xib + (size_t)(b * TLEN + t) * DINNER + blockIdx.x * 4) = o;
}

// ---------------- selective scan + fused dt_proj (streamed, bounded unroll) ----------
// grid (DINNER/4 = 384, BATCH), 512 threads; 8 waves x 32-step chunks.
__global__ __launch_bounds__(512) void scan_k(const unsigned short* __restrict__ xzT,
                                              const float* __restrict__ xdblT,
                                              const float* __restrict__ dpw,
                                              const float* __restrict__ dpb,
                                              const float* __restrict__ cw,
                                              const float* __restrict__ cb,
                                              const float* __restrict__ Alog,
                                              const float* __restrict__ Dsk,
                                              unsigned short* __restrict__ ybb) {
    __shared__ float dt_s[4][256];
    __shared__ float wdt_s[192];
    __shared__ float yl[4][260];
    __shared__ float cum[4][260];
    __shared__ float hL[8][4][16];
    __shared__ float Pb[8][4][16];
    __shared__ float Hin[8][4][16];

    int tid = threadIdx.x;
    int c = tid >> 6;
    int lane = tid & 63;
    int ch = lane >> 4;
    int n = lane & 15;
    int d0 = blockIdx.x * 4;
    int d = d0 + ch;
    int b = blockIdx.y;
    int tl0 = c * 32;

    // --- fused dt_proj prologue: dt_s[dd][t] = softplus(xdbl[t,:48]·dpw[d0+dd] + dpb)
    if (tid < 192) wdt_s[tid] = dpw[(size_t)d0 * DTRANK + tid];  // 4 rows contiguous
    __syncthreads();
    {
        int dd = tid >> 7;           // 0..3
        int tt = tid & 127;          // 0..127
        const float* wrow = &wdt_s[dd * DTRANK];
        const float* base = xdblT + (size_t)b * TLEN + tt;
        float a0 = 0.f, a1 = 0.f;
#pragma unroll 8
        for (int k = 0; k < DTRANK; ++k) {
            float w = wrow[k];
            a0 += w * base[(size_t)k * NTOK];
            a1 += w * base[(size_t)k * NTOK + 128];
        }
        float bias = dpb[d0 + dd];
        float v0 = a0 + bias, v1 = a1 + bias;
        v0 = (v0 > 0.f) ? v0 + log1pf(__expf(-v0)) : log1pf(__expf(v0));
        v1 = (v1 > 0.f) ? v1 + log1pf(__expf(-v1)) : log1pf(__expf(v1));
        dt_s[dd][tt] = v0;
        dt_s[dd][tt + 128] = v1;
    }
    __syncthreads();

    float a = -__expf(Alog[(size_t)d * NSTATE + n]);
    float Dv = Dsk[d];
    float w0 = cw[d * 4 + 0], w1 = cw[d * 4 + 1], w2 = cw[d * 4 + 2], w3 = cw[d * 4 + 3];
    float cbv = cb[d];
    const unsigned short* xzp = xzT + (size_t)d * NTOK + b * TLEN + tl0;
    const float* Bp = xdblT + (size_t)(DTRANK + n) * NTOK + b * TLEN + tl0;
    const float* Cp = xdblT + (size_t)(DTRANK + NSTATE + n) * NTOK + b * TLEN + tl0;

    float hm3 = 0.f, hm2 = 0.f, hm1 = 0.f;
    if (tl0 > 0) {
        ushort4 pv = *(const ushort4*)(xzp - 4);
        hm3 = b2f(pv.y); hm2 = b2f(pv.z); hm1 = b2f(pv.w);
    }

    float h = 0.f, cd = 0.f;
    for (int t8 = 0; t8 < 32; t8 += 8) {
        ushort4 xv0 = *(const ushort4*)(xzp + t8), xv1 = *(const ushort4*)(xzp + t8 + 4);
        float4 B0 = *(const float4*)(Bp + t8), B1 = *(const float4*)(Bp + t8 + 4);
        float4 C0 = *(const float4*)(Cp + t8), C1 = *(const float4*)(Cp + t8 + 4);
        float xw[11] = {hm3, hm2, hm1,
                        b2f(xv0.x), b2f(xv0.y), b2f(xv0.z), b2f(xv0.w),
                        b2f(xv1.x), b2f(xv1.y), b2f(xv1.z), b2f(xv1.w)};
        float Bs[8] = {B0.x, B0.y, B0.z, B0.w, B1.x, B1.y, B1.z, B1.w};
        float Cs[8] = {C0.x, C0.y, C0.z, C0.w, C1.x, C1.y, C1.z, C1.w};
#pragma unroll
        for (int u = 0; u < 8; ++u) {
            float sv = cbv + w0 * xw[u] + w1 * xw[u + 1] + w2 * xw[u + 2] + w3 * xw[u + 3];
            float xi = sv / (1.f + __expf(-sv));
            float dtv = dt_s[ch][tl0 + t8 + u];
            cd += dtv;
            float dA = __expf(dtv * a);
            h = dA * h + (dtv * xi) * Bs[u];
            float p = red16(h * Cs[u]);
            if (n == 0) {
                yl[ch][tl0 + t8 + u] = p + Dv * xi;
                cum[ch][tl0 + t8 + u] = cd;
            }
        }
        hm3 = xw[8]; hm2 = xw[9]; hm1 = xw[10];
    }
    hL[c][ch][n] = h;
    Pb[c][ch][n] = __expf(a * cd);
    __syncthreads();
    if (c == 0) {
        float H = 0.f;
        Hin[0][ch][n] = 0.f;
#pragma unroll
        for (int cc = 1; cc < 8; ++cc) {
            H = Pb[cc - 1][ch][n] * H + hL[cc - 1][ch][n];
            Hin[cc][ch][n] = H;
        }
    }
    __syncthreads();
    float Hv = Hin[c][ch][n];
    const unsigned short* zp = xzT + (size_t)(DINNER + d) * NTOK + b * TLEN + tl0;
    for (int t8 = 0; t8 < 32; t8 += 8) {
        float4 C0 = *(const float4*)(Cp + t8), C1 = *(const float4*)(Cp + t8 + 4);
        ushort4 zv0 = *(const ushort4*)(zp + t8), zv1 = *(const ushort4*)(zp + t8 + 4);
        float Cs[8] = {C0.x, C0.y, C0.z, C0.w, C1.x, C1.y, C1.z, C1.w};
        float zs[8] = {b2f(zv0.x), b2f(zv0.y), b2f(zv0.z), b2f(zv0.w),
                       b2f(zv1.x), b2f(zv1.y), b2f(zv1.z), b2f(zv1.w)};
#pragma unroll
        for (int u = 0; u < 8; ++u) {
            float cdt = cum[ch][tl0 + t8 + u];
            float corr = red16(Cs[u] * __expf(a * cdt) * Hv);
            if (n == 0) {
                float y = yl[ch][tl0 + t8 + u] + corr;
                float zz = zs[u];
                y *= zz / (1.f + __expf(-zz));
                yl[ch][tl0 + t8 + u] = y;
            }
        }
    }
    __syncthreads();
    if (tid < 256) {
        int t = tid;
        ushort4 o;
        o.x = f2b(yl[0][t]);
        o.y = f2b(yl[1][t]);
        o.z = f2b(yl[2][t]);
        o.w = f2b(yl[3][t]);
        *(ushort4*)(ybb + (size_t)(b * TLEN + t) * DINNER + blockIdx.x * 4) = o;
    }
}

// ---------------- RMSNorm ----------------
__global__ __launch_bounds__(256) void rmsnorm_k(const float* __restrict__ x,
                                                 const float* __restrict__ nw,
                                                 float* __restrict__ out) {
    int row = blockIdx.x;
    const float* xr = x + (size_t)row * DMODEL;
    int tid = threadIdx.x;
    float s = 0.f;
    for (int d = tid; d < DMODEL; d += 256) {
        float v = xr[d];
        s += v * v;
    }
#pragma unroll
    for (int off = 32; off >= 1; off >>= 1) s += __shfl_down(s, off);
    __shared__ float red[4];
    __shared__ float scale;
    int wid = tid >> 6, lane = tid & 63;
    if (lane == 0) red[wid] = s;
    __syncthreads();
    if (tid == 0) {
        float tot = red[0] + red[1] + red[2] + red[3];
        scale = rsqrtf(tot / (float)DMODEL + 1e-5f);
    }
    __syncthreads();
    float sc = scale;
    for (int d = tid; d < DMODEL; d += 256)
        out[(size_t)row * DMODEL + d] = xr[d] * sc * nw[d];
}

extern "C" void kernel_launch(void* const* d_in, const int* in_sizes, int n_in,
                              void* d_out, int out_size, void* d_ws, size_t ws_size,
                              hipStream_t stream) {
    const int* ids = (const int*)d_in[0];
    const float* emb = (const float*)d_in[1];
    const float* pos = (const float*)d_in[2];
    const float* ipw = (const float*)d_in[3];
    const float* cw = (const float*)d_in[4];
    const float* cb = (const float*)d_in[5];
    const float* xpw = (const float*)d_in[6];
    const float* dpw = (const float*)d_in[7];
    const float* dpb = (const float*)d_in[8];
    const float* Alog = (const float*)d_in[9];
    const float* Dsk = (const float*)d_in[10];
    const float* opw = (const float*)d_in[11];
    const float* nw = (const float*)d_in[12];

    float* x = (float*)d_ws;                             // 786432 f32
    float* xdblT = x + 786432;                           // 81920 f32
    unsigned short* xb = (unsigned short*)(xdblT + 81920);  // 786432
    unsigned short* xzT = xb + 786432;                   // 3145728
    unsigned short* xib = xzT + 3145728;                 // 1572864
    unsigned short* ybb = xib + 1572864;                 // 1572864
    unsigned short* w_all = ybb + 1572864;               // 4 * WL

    prep_k<<<NB_WALL + NB_E, 256, 0, stream>>>(ipw, opw, xpw, ids, emb, pos,
                                               w_all, x, xb);

    for (int l = 0; l < NLAYER; ++l) {
        const unsigned short* w_ip = w_all + (size_t)l * WL;
        const unsigned short* w_op = w_ip + S_IP;
        const unsigned short* w_xp = w_op + S_OP;
        const float* cw_l = cw + (size_t)l * DINNER * 4;
        const float* cb_l = cb + (size_t)l * DINNER;
        const float* dpw_l = dpw + (size_t)l * DINNER * DTRANK;
        const float* dpb_l = dpb + (size_t)l * DINNER;
        const float* Alog_l = Alog + (size_t)l * DINNER * NSTATE;
        const float* Dsk_l = Dsk + (size_t)l * DINNER;

        // in_proj: xzT bf16 [3072][1024], 128x128 tiles
        ipgemm_k<<<dim3(3072 / 128, NTOK / 128), 256, 0, stream>>>(w_ip, xb, xzT);
        // conv + silu -> xib bf16
        conv_k<<<dim3(DINNER / 4, BATCH), 256, 0, stream>>>(xzT, cw_l, cb_l, xib);
        // x_proj: xdblT f32 [80][1024] (all feature rows, transposed)
        mgemm_k<1><<<dim3(2, NTOK / 64), 256, 0, stream>>>(
            w_xp, DINNER, xib, DINNER, DINNER, xdblT, nullptr);
        // scan (+fused dt_proj prologue)
        scan_k<<<dim3(DINNER / 4, BATCH), 512, 0, stream>>>(
            xzT, xdblT, dpw_l, dpb_l, cw_l, cb_l, Alog_l, Dsk_l, ybb);
        // out_proj: x += y @ opw^T, xb = bf16(x)
        mgemm_k<3><<<dim3(NTOK / 64, DMODEL / 64), 256, 0, stream>>>(
            ybb, DINNER, w_op, DINNER, DINNER, x, xb);
    }

    rmsnorm_k<<<NTOK, 256, 0, stream>>>(x, nw, (float*)d_out);
}

// Round 13
// 501.872 us; speedup vs baseline: 4.5604x; 1.0200x over previous
//
#include <hip/hip_runtime.h>
#include <math.h>

#define TLEN 256
#define BATCH 4
#define DMODEL 768
#define DINNER 1536
#define NSTATE 16
#define DTRANK 48
#define NLAYER 4
#define NTOK 1024

#define S_IP 2359296
#define S_OP 1179648
#define S_XP2 196608            /* 128 x 1536 zero-padded */
#define WL (S_IP + S_OP + S_XP2)
#define NB_W (WL / 1024)
#define NB_WALL (NB_W * NLAYER)
#define NB_E (NTOK * DMODEL / 256)

typedef __bf16 bf16x8 __attribute__((ext_vector_type(8)));
typedef float f32x4 __attribute__((ext_vector_type(4)));

__device__ inline unsigned short f2b(float f) {
    union { float f; unsigned u; } v;
    v.f = f;
    unsigned r = (v.u + 0x7fffu + ((v.u >> 16) & 1u)) >> 16;  // RNE
    return (unsigned short)r;
}
__device__ inline float b2f(unsigned short u) {
    union { unsigned u; float f; } v;
    v.u = ((unsigned)u) << 16;
    return v.f;
}

__device__ inline void gload16(const void* g, void* l) {
    __builtin_amdgcn_global_load_lds(
        (const __attribute__((address_space(1))) void*)g,
        (__attribute__((address_space(3))) void*)l, 16, 0, 0);
}

// 16-lane sum via DPP (quad xor1, xor2, then row_ror 4, 8) — no DS ops.
__device__ inline float red16(float p) {
    p += __int_as_float(__builtin_amdgcn_update_dpp(0, __float_as_int(p), 0xB1, 0xf, 0xf, true));
    p += __int_as_float(__builtin_amdgcn_update_dpp(0, __float_as_int(p), 0x4E, 0xf, 0xf, true));
    p += __int_as_float(__builtin_amdgcn_update_dpp(0, __float_as_int(p), 0x124, 0xf, 0xf, true));
    p += __int_as_float(__builtin_amdgcn_update_dpp(0, __float_as_int(p), 0x128, 0xf, 0xf, true));
    return p;
}

// ---------------- prep: all-layer weight convert + embed, one dispatch ----------------
__global__ __launch_bounds__(256) void prep_k(const float* __restrict__ ipw,
                                              const float* __restrict__ opw,
                                              const float* __restrict__ xpw,
                                              const int* __restrict__ ids,
                                              const float* __restrict__ emb,
                                              const float* __restrict__ pos,
                                              unsigned short* __restrict__ w_all,
                                              float* __restrict__ x,
                                              unsigned short* __restrict__ xb) {
    int bid = blockIdx.x;
    int tid = threadIdx.x;
    if (bid >= NB_WALL) {  // embed
        int idx = (bid - NB_WALL) * 256 + tid;
        int d = idx % DMODEL;
        int bt = idx / DMODEL;
        int t = bt % TLEN;
        float v = emb[(size_t)ids[bt] * DMODEL + d] + pos[t * DMODEL + d];
        x[idx] = v;
        xb[idx] = f2b(v);
        return;
    }
    int l = bid / NB_W;
    int i4 = ((bid % NB_W) * 256 + tid) * 4;
    unsigned short* wl = w_all + (size_t)l * WL;
    if (i4 < S_IP) {
        float4 v = *(const float4*)(ipw + (size_t)l * S_IP + i4);
        ushort4 o; o.x = f2b(v.x); o.y = f2b(v.y); o.z = f2b(v.z); o.w = f2b(v.w);
        *(ushort4*)(wl + i4) = o;
    } else if (i4 < S_IP + S_OP) {
        int i = i4 - S_IP;
        float4 v = *(const float4*)(opw + (size_t)l * S_OP + i);
        ushort4 o; o.x = f2b(v.x); o.y = f2b(v.y); o.z = f2b(v.z); o.w = f2b(v.w);
        *(ushort4*)(wl + S_IP + i) = o;
    } else {
        int i = i4 - S_IP - S_OP;
        int r = i / 1536, k = i % 1536;
        ushort4 o = {0, 0, 0, 0};
        if (r < 80) {
            float4 v = *(const float4*)(xpw + (size_t)l * (80 * 1536) + (size_t)r * 1536 + k);
            o.x = f2b(v.x); o.y = f2b(v.y); o.z = f2b(v.z); o.w = f2b(v.w);
        }
        *(ushort4*)(wl + S_IP + S_OP + i) = o;
    }
}

// ---------------- in_proj GEMM: 128x128 tile, swizzled LDS + 3-buf counted vmcnt ----
__global__ __launch_bounds__(256) void ipgemm_k(const unsigned short* __restrict__ A,
                                                const unsigned short* __restrict__ B,
                                                unsigned short* __restrict__ o1) {
    __shared__ __align__(16) unsigned short Ab[3][128 * 64];
    __shared__ __align__(16) unsigned short Bb[3][128 * 64];

    int tid = threadIdx.x;
    int lane = tid & 63;
    int wave = tid >> 6;
    int wm = (wave >> 1) * 64;
    int wn = (wave & 1) * 64;
    int bm = blockIdx.x * 128;
    int bn = blockIdx.y * 128;
    int fr = lane & 15;
    int fq = lane >> 4;
    int fk = fq * 8;
    int srow = lane >> 3;                 // 0..7
    int scol = (lane & 7) * 8;            // chunk*8 elems
    int gcol = scol ^ (srow << 3);        // pre-swizzled global chunk (rule #21)
    int sw = (fr & 7) << 3;               // read-side swizzle

    f32x4 acc[4][4] = {};

    auto stage = [&](int s, int k0) {     // 8 gload16 per wave
#pragma unroll
        for (int c = 0; c < 4; ++c) {
            int r = wave * 32 + c * 8;
            gload16(A + (size_t)(bm + r + srow) * DMODEL + k0 + gcol, &Ab[s][r * 64]);
            gload16(B + (size_t)(bn + r + srow) * DMODEL + k0 + gcol, &Bb[s][r * 64]);
        }
    };

    const int nk = DMODEL / 64;  // 12
    stage(0, 0);
    stage(1, 64);

    for (int t = 0; t < nk; ++t) {
        if (t + 1 < nk) {
            asm volatile("s_waitcnt vmcnt(8)" ::: "memory");   // stage t landed
        } else {
            asm volatile("s_waitcnt vmcnt(0)" ::: "memory");
        }
        __builtin_amdgcn_s_barrier();
        if (t + 2 < nk) stage((t + 2) % 3, (t + 2) * 64);
        int cur = t % 3;
#pragma unroll
        for (int ks = 0; ks < 2; ++ks) {
            int kk = ks * 32 + fk;
            bf16x8 af[4], bfr[4];
#pragma unroll
            for (int i = 0; i < 4; ++i)
                af[i] = *(const bf16x8*)&Ab[cur][(wm + i * 16 + fr) * 64 + (kk ^ sw)];
#pragma unroll
            for (int j = 0; j < 4; ++j)
                bfr[j] = *(const bf16x8*)&Bb[cur][(wn + j * 16 + fr) * 64 + (kk ^ sw)];
#pragma unroll
            for (int i = 0; i < 4; ++i)
#pragma unroll
                for (int j = 0; j < 4; ++j)
                    acc[i][j] = __builtin_amdgcn_mfma_f32_16x16x32_bf16(
                        af[i], bfr[j], acc[i][j], 0, 0, 0);
        }
        __builtin_amdgcn_s_barrier();     // readers done before buffer reuse
    }

#pragma unroll
    for (int i = 0; i < 4; ++i) {
#pragma unroll
        for (int j = 0; j < 4; ++j) {
            int lc = wn + j * 16 + fr;
#pragma unroll
            for (int q = 0; q < 4; ++q) {
                int lr = wm + i * 16 + fq * 4 + q;
                o1[(size_t)(bm + lr) * NTOK + bn + lc] = f2b(acc[i][j][q]);
            }
        }
    }
}

// ---------------- bf16 MFMA GEMM, BM=64, swizzled LDS + 3-buf counted vmcnt --------
// MODE 1: o0 = xdblT f32 [80][1024] (rows < 80)                          (x_proj)
// MODE 3: o0 = x [1024][768] f32 accumulate, o1 = xb bf16 mirror         (out_proj)
template <int MODE>
__global__ __launch_bounds__(256) void mgemm_k(const unsigned short* __restrict__ A, int lda,
                                               const unsigned short* __restrict__ B, int ldb,
                                               int K,
                                               float* __restrict__ o0,
                                               unsigned short* __restrict__ o1) {
    __shared__ __align__(16) unsigned short Ab[3][64 * 64];
    __shared__ __align__(16) unsigned short Bb[3][64 * 64];

    int tid = threadIdx.x;
    int lane = tid & 63;
    int wave = tid >> 6;
    int wm = (wave >> 1) * 32;
    int wn = (wave & 1) * 32;
    int bm = blockIdx.x * 64;
    int bn = blockIdx.y * 64;
    int fr = lane & 15;
    int fq = lane >> 4;
    int fk = fq * 8;
    int srow = lane >> 3;
    int scol = (lane & 7) * 8;
    int gcol = scol ^ (srow << 3);
    int sw = (fr & 7) << 3;

    f32x4 acc[2][2] = {};

    auto stage = [&](int s, int k0) {     // 4 gload16 per wave
#pragma unroll
        for (int c = 0; c < 2; ++c) {
            int r = wave * 16 + c * 8;
            gload16(A + (size_t)(bm + r + srow) * lda + k0 + gcol, &Ab[s][r * 64]);
            gload16(B + (size_t)(bn + r + srow) * ldb + k0 + gcol, &Bb[s][r * 64]);
        }
    };

    int nk = K >> 6;
    stage(0, 0);
    stage(1, 64);

    for (int t = 0; t < nk; ++t) {
        if (t + 1 < nk) {
            asm volatile("s_waitcnt vmcnt(4)" ::: "memory");
        } else {
            asm volatile("s_waitcnt vmcnt(0)" ::: "memory");
        }
        __builtin_amdgcn_s_barrier();
        if (t + 2 < nk) stage((t + 2) % 3, (t + 2) * 64);
        int cur = t % 3;
#pragma unroll
        for (int ks = 0; ks < 2; ++ks) {
            int kk = ks * 32 + fk;
            bf16x8 af[2], bfr[2];
#pragma unroll
            for (int i = 0; i < 2; ++i)
                af[i] = *(const bf16x8*)&Ab[cur][(wm + i * 16 + fr) * 64 + (kk ^ sw)];
#pragma unroll
            for (int j = 0; j < 2; ++j)
                bfr[j] = *(const bf16x8*)&Bb[cur][(wn + j * 16 + fr) * 64 + (kk ^ sw)];
#pragma unroll
            for (int i = 0; i < 2; ++i)
#pragma unroll
                for (int j = 0; j < 2; ++j)
                    acc[i][j] = __builtin_amdgcn_mfma_f32_16x16x32_bf16(
                        af[i], bfr[j], acc[i][j], 0, 0, 0);
        }
        __builtin_amdgcn_s_barrier();
    }

#pragma unroll
    for (int i = 0; i < 2; ++i) {
#pragma unroll
        for (int j = 0; j < 2; ++j) {
            int lc = wn + j * 16 + fr;
#pragma unroll
            for (int q = 0; q < 4; ++q) {
                int lr = wm + i * 16 + fq * 4 + q;
                float v = acc[i][j][q];
                if (MODE == 1) {
                    int f = bm + lr;
                    if (f < 80) o0[(size_t)f * NTOK + bn + lc] = v;
                } else {  // MODE 3: residual accumulate + bf16 mirror
                    size_t idx = (size_t)(bm + lr) * DMODEL + bn + lc;
                    float nv = o0[idx] + v;
                    o0[idx] = nv;
                    o1[idx] = f2b(nv);
                }
            }
        }
    }
}

// ---------------- causal dwconv(K=4) + bias + SiLU, bf16 in/out ----------------
__global__ __launch_bounds__(256) void conv_k(const unsigned short* __restrict__ xzT,
                                              const float* __restrict__ cw,
                                              const float* __restrict__ cb,
                                              unsigned short* __restrict__ xib) {
    __shared__ unsigned short tile[4][256];
    int tid = threadIdx.x;
    int ch = tid >> 6;
    int d = blockIdx.x * 4 + ch;
    int b = blockIdx.y;
    int t0 = (tid & 63) * 4;
    const unsigned short* src = xzT + (size_t)d * NTOK + b * TLEN + t0;
    ushort4 cur = *(const ushort4*)src;
    ushort4 prev = {0, 0, 0, 0};
    if (t0 > 0) prev = *(const ushort4*)(src - 4);
    float w0 = cw[d * 4 + 0], w1 = cw[d * 4 + 1], w2 = cw[d * 4 + 2], w3 = cw[d * 4 + 3];
    float bb = cb[d];
    float xw[8] = {b2f(prev.x), b2f(prev.y), b2f(prev.z), b2f(prev.w),
                   b2f(cur.x), b2f(cur.y), b2f(cur.z), b2f(cur.w)};
#pragma unroll
    for (int u = 0; u < 4; ++u) {
        float s = bb + w0 * xw[u + 1] + w1 * xw[u + 2] + w2 * xw[u + 3] + w3 * xw[u + 4];
        float v = s / (1.f + __expf(-s));
        tile[ch][t0 + u] = f2b(v);
    }
    __syncthreads();
    int t = tid;
    ushort4 o;
    o.x = tile[0][t]; o.y = tile[1][t]; o.z = tile[2][t]; o.w = tile[3][t];
    *(ushort4*)(xib + (size_t)(b * TLEN + t) * DINNER + blockIdx.x * 4) = o;
}

// ---------------- selective scan + fused dt_proj (streamed, bounded unroll) ----------
__global__ __launch_bounds__(512) void scan_k(const unsigned short* __restrict__ xzT,
                                              const float* __restrict__ xdblT,
                                              const float* __restrict__ dpw,
                                              const float* __restrict__ dpb,
                                              const float* __restrict__ cw,
                                              const float* __restrict__ cb,
                                              const float* __restrict__ Alog,
                                              const float* __restrict__ Dsk,
                                              unsigned short* __restrict__ ybb) {
    __shared__ float dt_s[4][256];
    __shared__ float wdt_s[192];
    __shared__ float yl[4][260];
    __shared__ float cum[4][260];
    __shared__ float hL[8][4][16];
    __shared__ float Pb[8][4][16];
    __shared__ float Hin[8][4][16];

    int tid = threadIdx.x;
    int c = tid >> 6;
    int lane = tid & 63;
    int ch = lane >> 4;
    int n = lane & 15;
    int d0 = blockIdx.x * 4;
    int d = d0 + ch;
    int b = blockIdx.y;
    int tl0 = c * 32;

    if (tid < 192) wdt_s[tid] = dpw[(size_t)d0 * DTRANK + tid];
    __syncthreads();
    {
        int dd = tid >> 7;
        int tt = tid & 127;
        const float* wrow = &wdt_s[dd * DTRANK];
        const float* base = xdblT + (size_t)b * TLEN + tt;
        float a0 = 0.f, a1 = 0.f;
#pragma unroll 8
        for (int k = 0; k < DTRANK; ++k) {
            float w = wrow[k];
            a0 += w * base[(size_t)k * NTOK];
            a1 += w * base[(size_t)k * NTOK + 128];
        }
        float bias = dpb[d0 + dd];
        float v0 = a0 + bias, v1 = a1 + bias;
        v0 = (v0 > 0.f) ? v0 + log1pf(__expf(-v0)) : log1pf(__expf(v0));
        v1 = (v1 > 0.f) ? v1 + log1pf(__expf(-v1)) : log1pf(__expf(v1));
        dt_s[dd][tt] = v0;
        dt_s[dd][tt + 128] = v1;
    }
    __syncthreads();

    float a = -__expf(Alog[(size_t)d * NSTATE + n]);
    float Dv = Dsk[d];
    float w0 = cw[d * 4 + 0], w1 = cw[d * 4 + 1], w2 = cw[d * 4 + 2], w3 = cw[d * 4 + 3];
    float cbv = cb[d];
    const unsigned short* xzp = xzT + (size_t)d * NTOK + b * TLEN + tl0;
    const float* Bp = xdblT + (size_t)(DTRANK + n) * NTOK + b * TLEN + tl0;
    const float* Cp = xdblT + (size_t)(DTRANK + NSTATE + n) * NTOK + b * TLEN + tl0;

    float hm3 = 0.f, hm2 = 0.f, hm1 = 0.f;
    if (tl0 > 0) {
        ushort4 pv = *(const ushort4*)(xzp - 4);
        hm3 = b2f(pv.y); hm2 = b2f(pv.z); hm1 = b2f(pv.w);
    }

    float h = 0.f, cd = 0.f;
    for (int t8 = 0; t8 < 32; t8 += 8) {
        ushort4 xv0 = *(const ushort4*)(xzp + t8), xv1 = *(const ushort4*)(xzp + t8 + 4);
        float4 B0 = *(const float4*)(Bp + t8), B1 = *(const float4*)(Bp + t8 + 4);
        float4 C0 = *(const float4*)(Cp + t8), C1 = *(const float4*)(Cp + t8 + 4);
        float xw[11] = {hm3, hm2, hm1,
                        b2f(xv0.x), b2f(xv0.y), b2f(xv0.z), b2f(xv0.w),
                        b2f(xv1.x), b2f(xv1.y), b2f(xv1.z), b2f(xv1.w)};
        float Bs[8] = {B0.x, B0.y, B0.z, B0.w, B1.x, B1.y, B1.z, B1.w};
        float Cs[8] = {C0.x, C0.y, C0.z, C0.w, C1.x, C1.y, C1.z, C1.w};
#pragma unroll
        for (int u = 0; u < 8; ++u) {
            float sv = cbv + w0 * xw[u] + w1 * xw[u + 1] + w2 * xw[u + 2] + w3 * xw[u + 3];
            float xi = sv / (1.f + __expf(-sv));
            float dtv = dt_s[ch][tl0 + t8 + u];
            cd += dtv;
            float dA = __expf(dtv * a);
            h = dA * h + (dtv * xi) * Bs[u];
            float p = red16(h * Cs[u]);
            if (n == 0) {
                yl[ch][tl0 + t8 + u] = p + Dv * xi;
                cum[ch][tl0 + t8 + u] = cd;
            }
        }
        hm3 = xw[8]; hm2 = xw[9]; hm1 = xw[10];
    }
    hL[c][ch][n] = h;
    Pb[c][ch][n] = __expf(a * cd);
    __syncthreads();
    if (c == 0) {
        float H = 0.f;
        Hin[0][ch][n] = 0.f;
#pragma unroll
        for (int cc = 1; cc < 8; ++cc) {
            H = Pb[cc - 1][ch][n] * H + hL[cc - 1][ch][n];
            Hin[cc][ch][n] = H;
        }
    }
    __syncthreads();
    float Hv = Hin[c][ch][n];
    const unsigned short* zp = xzT + (size_t)(DINNER + d) * NTOK + b * TLEN + tl0;
    for (int t8 = 0; t8 < 32; t8 += 8) {
        float4 C0 = *(const float4*)(Cp + t8), C1 = *(const float4*)(Cp + t8 + 4);
        ushort4 zv0 = *(const ushort4*)(zp + t8), zv1 = *(const ushort4*)(zp + t8 + 4);
        float Cs[8] = {C0.x, C0.y, C0.z, C0.w, C1.x, C1.y, C1.z, C1.w};
        float zs[8] = {b2f(zv0.x), b2f(zv0.y), b2f(zv0.z), b2f(zv0.w),
                       b2f(zv1.x), b2f(zv1.y), b2f(zv1.z), b2f(zv1.w)};
#pragma unroll
        for (int u = 0; u < 8; ++u) {
            float cdt = cum[ch][tl0 + t8 + u];
            float corr = red16(Cs[u] * __expf(a * cdt) * Hv);
            if (n == 0) {
                float y = yl[ch][tl0 + t8 + u] + corr;
                float zz = zs[u];
                y *= zz / (1.f + __expf(-zz));
                yl[ch][tl0 + t8 + u] = y;
            }
        }
    }
    __syncthreads();
    if (tid < 256) {
        int t = tid;
        ushort4 o;
        o.x = f2b(yl[0][t]);
        o.y = f2b(yl[1][t]);
        o.z = f2b(yl[2][t]);
        o.w = f2b(yl[3][t]);
        *(ushort4*)(ybb + (size_t)(b * TLEN + t) * DINNER + blockIdx.x * 4) = o;
    }
}

// ---------------- RMSNorm ----------------
__global__ __launch_bounds__(256) void rmsnorm_k(const float* __restrict__ x,
                                                 const float* __restrict__ nw,
                                                 float* __restrict__ out) {
    int row = blockIdx.x;
    const float* xr = x + (size_t)row * DMODEL;
    int tid = threadIdx.x;
    float s = 0.f;
    for (int d = tid; d < DMODEL; d += 256) {
        float v = xr[d];
        s += v * v;
    }
#pragma unroll
    for (int off = 32; off >= 1; off >>= 1) s += __shfl_down(s, off);
    __shared__ float red[4];
    __shared__ float scale;
    int wid = tid >> 6, lane = tid & 63;
    if (lane == 0) red[wid] = s;
    __syncthreads();
    if (tid == 0) {
        float tot = red[0] + red[1] + red[2] + red[3];
        scale = rsqrtf(tot / (float)DMODEL + 1e-5f);
    }
    __syncthreads();
    float sc = scale;
    for (int d = tid; d < DMODEL; d += 256)
        out[(size_t)row * DMODEL + d] = xr[d] * sc * nw[d];
}

extern "C" void kernel_launch(void* const* d_in, const int* in_sizes, int n_in,
                              void* d_out, int out_size, void* d_ws, size_t ws_size,
                              hipStream_t stream) {
    const int* ids = (const int*)d_in[0];
    const float* emb = (const float*)d_in[1];
    const float* pos = (const float*)d_in[2];
    const float* ipw = (const float*)d_in[3];
    const float* cw = (const float*)d_in[4];
    const float* cb = (const float*)d_in[5];
    const float* xpw = (const float*)d_in[6];
    const float* dpw = (const float*)d_in[7];
    const float* dpb = (const float*)d_in[8];
    const float* Alog = (const float*)d_in[9];
    const float* Dsk = (const float*)d_in[10];
    const float* opw = (const float*)d_in[11];
    const float* nw = (const float*)d_in[12];

    float* x = (float*)d_ws;                             // 786432 f32
    float* xdblT = x + 786432;                           // 81920 f32
    unsigned short* xb = (unsigned short*)(xdblT + 81920);  // 786432
    unsigned short* xzT = xb + 786432;                   // 3145728
    unsigned short* xib = xzT + 3145728;                 // 1572864
    unsigned short* ybb = xib + 1572864;                 // 1572864
    unsigned short* w_all = ybb + 1572864;               // 4 * WL

    prep_k<<<NB_WALL + NB_E, 256, 0, stream>>>(ipw, opw, xpw, ids, emb, pos,
                                               w_all, x, xb);

    for (int l = 0; l < NLAYER; ++l) {
        const unsigned short* w_ip = w_all + (size_t)l * WL;
        const unsigned short* w_op = w_ip + S_IP;
        const unsigned short* w_xp = w_op + S_OP;
        const float* cw_l = cw + (size_t)l * DINNER * 4;
        const float* cb_l = cb + (size_t)l * DINNER;
        const float* dpw_l = dpw + (size_t)l * DINNER * DTRANK;
        const float* dpb_l = dpb + (size_t)l * DINNER;
        const float* Alog_l = Alog + (size_t)l * DINNER * NSTATE;
        const float* Dsk_l = Dsk + (size_t)l * DINNER;

        // in_proj: xzT bf16 [3072][1024]
        ipgemm_k<<<dim3(3072 / 128, NTOK / 128), 256, 0, stream>>>(w_ip, xb, xzT);
        // conv + silu -> xib bf16
        conv_k<<<dim3(DINNER / 4, BATCH), 256, 0, stream>>>(xzT, cw_l, cb_l, xib);
        // x_proj: xdblT f32 [80][1024]
        mgemm_k<1><<<dim3(2, NTOK / 64), 256, 0, stream>>>(
            w_xp, DINNER, xib, DINNER, DINNER, xdblT, nullptr);
        // scan (+fused dt_proj prologue)
        scan_k<<<dim3(DINNER / 4, BATCH), 512, 0, stream>>>(
            xzT, xdblT, dpw_l, dpb_l, cw_l, cb_l, Alog_l, Dsk_l, ybb);
        // out_proj: x += y @ opw^T, xb = bf16(x)
        mgemm_k<3><<<dim3(NTOK / 64, DMODEL / 64), 256, 0, stream>>>(
            ybb, DINNER, w_op, DINNER, DINNER, x, xb);
    }

    rmsnorm_k<<<NTOK, 256, 0, stream>>>(x, nw, (float*)d_out);
}

// Round 14
// 449.816 us; speedup vs baseline: 5.0881x; 1.1157x over previous
//
#include <hip/hip_runtime.h>
#include <math.h>

#define TLEN 256
#define BATCH 4
#define DMODEL 768
#define DINNER 1536
#define NSTATE 16
#define DTRANK 48
#define NLAYER 4
#define NTOK 1024

#define S_IP 2359296
#define S_OP 1179648
#define S_XP2 196608            /* 128 x 1536 zero-padded */
#define WL (S_IP + S_OP + S_XP2)
#define NB_W (WL / 1024)
#define NB_WALL (NB_W * NLAYER)
#define NB_E (NTOK * DMODEL / 256)

typedef __bf16 bf16x8 __attribute__((ext_vector_type(8)));
typedef float f32x4 __attribute__((ext_vector_type(4)));

__device__ inline unsigned short f2b(float f) {
    union { float f; unsigned u; } v;
    v.f = f;
    unsigned r = (v.u + 0x7fffu + ((v.u >> 16) & 1u)) >> 16;  // RNE
    return (unsigned short)r;
}
__device__ inline float b2f(unsigned short u) {
    union { unsigned u; float f; } v;
    v.u = ((unsigned)u) << 16;
    return v.f;
}

__device__ inline void gload16(const void* g, void* l) {
    __builtin_amdgcn_global_load_lds(
        (const __attribute__((address_space(1))) void*)g,
        (__attribute__((address_space(3))) void*)l, 16, 0, 0);
}

// 16-lane sum via DPP (quad xor1, xor2, then row_ror 4, 8) — no DS ops.
__device__ inline float red16(float p) {
    p += __int_as_float(__builtin_amdgcn_update_dpp(0, __float_as_int(p), 0xB1, 0xf, 0xf, true));
    p += __int_as_float(__builtin_amdgcn_update_dpp(0, __float_as_int(p), 0x4E, 0xf, 0xf, true));
    p += __int_as_float(__builtin_amdgcn_update_dpp(0, __float_as_int(p), 0x124, 0xf, 0xf, true));
    p += __int_as_float(__builtin_amdgcn_update_dpp(0, __float_as_int(p), 0x128, 0xf, 0xf, true));
    return p;
}

// ---------------- prep: all-layer weight convert + embed, one dispatch ----------------
__global__ __launch_bounds__(256) void prep_k(const float* __restrict__ ipw,
                                              const float* __restrict__ opw,
                                              const float* __restrict__ xpw,
                                              const int* __restrict__ ids,
                                              const float* __restrict__ emb,
                                              const float* __restrict__ pos,
                                              unsigned short* __restrict__ w_all,
                                              float* __restrict__ x,
                                              unsigned short* __restrict__ xb) {
    int bid = blockIdx.x;
    int tid = threadIdx.x;
    if (bid >= NB_WALL) {  // embed
        int idx = (bid - NB_WALL) * 256 + tid;
        int d = idx % DMODEL;
        int bt = idx / DMODEL;
        int t = bt % TLEN;
        float v = emb[(size_t)ids[bt] * DMODEL + d] + pos[t * DMODEL + d];
        x[idx] = v;
        xb[idx] = f2b(v);
        return;
    }
    int l = bid / NB_W;
    int i4 = ((bid % NB_W) * 256 + tid) * 4;
    unsigned short* wl = w_all + (size_t)l * WL;
    if (i4 < S_IP) {
        float4 v = *(const float4*)(ipw + (size_t)l * S_IP + i4);
        ushort4 o; o.x = f2b(v.x); o.y = f2b(v.y); o.z = f2b(v.z); o.w = f2b(v.w);
        *(ushort4*)(wl + i4) = o;
    } else if (i4 < S_IP + S_OP) {
        int i = i4 - S_IP;
        float4 v = *(const float4*)(opw + (size_t)l * S_OP + i);
        ushort4 o; o.x = f2b(v.x); o.y = f2b(v.y); o.z = f2b(v.z); o.w = f2b(v.w);
        *(ushort4*)(wl + S_IP + i) = o;
    } else {
        int i = i4 - S_IP - S_OP;
        int r = i / 1536, k = i % 1536;
        ushort4 o = {0, 0, 0, 0};
        if (r < 80) {
            float4 v = *(const float4*)(xpw + (size_t)l * (80 * 1536) + (size_t)r * 1536 + k);
            o.x = f2b(v.x); o.y = f2b(v.y); o.z = f2b(v.z); o.w = f2b(v.w);
        }
        *(ushort4*)(wl + S_IP + S_OP + i) = o;
    }
}

// ---------------- in_proj GEMM: 128x128 tile, swizzled LDS + 3-buf counted vmcnt ----
// Also zero-inits xdblT for the split-K x_proj that follows.
__global__ __launch_bounds__(256) void ipgemm_k(const unsigned short* __restrict__ A,
                                                const unsigned short* __restrict__ B,
                                                unsigned short* __restrict__ o1,
                                                float* __restrict__ xdblT) {
    __shared__ __align__(16) unsigned short Ab[3][128 * 64];
    __shared__ __align__(16) unsigned short Bb[3][128 * 64];

    int tid = threadIdx.x;
    {   // zero xdblT (81920 f32 = 40960 float2) across 192 blocks
        int unit = (blockIdx.x * gridDim.y + blockIdx.y) * 256 + tid;
        if (unit < 40960) {
            float2 z = {0.f, 0.f};
            *(float2*)(xdblT + unit * 2) = z;
        }
    }
    int lane = tid & 63;
    int wave = tid >> 6;
    int wm = (wave >> 1) * 64;
    int wn = (wave & 1) * 64;
    int bm = blockIdx.x * 128;
    int bn = blockIdx.y * 128;
    int fr = lane & 15;
    int fq = lane >> 4;
    int fk = fq * 8;
    int srow = lane >> 3;                 // 0..7
    int scol = (lane & 7) * 8;            // chunk*8 elems
    int gcol = scol ^ (srow << 3);        // pre-swizzled global chunk (rule #21)
    int sw = (fr & 7) << 3;               // read-side swizzle

    f32x4 acc[4][4] = {};

    auto stage = [&](int s, int k0) {     // 8 gload16 per wave
#pragma unroll
        for (int c = 0; c < 4; ++c) {
            int r = wave * 32 + c * 8;
            gload16(A + (size_t)(bm + r + srow) * DMODEL + k0 + gcol, &Ab[s][r * 64]);
            gload16(B + (size_t)(bn + r + srow) * DMODEL + k0 + gcol, &Bb[s][r * 64]);
        }
    };

    const int nk = DMODEL / 64;  // 12
    stage(0, 0);
    stage(1, 64);

    for (int t = 0; t < nk; ++t) {
        if (t + 1 < nk) {
            asm volatile("s_waitcnt vmcnt(8)" ::: "memory");   // stage t landed
        } else {
            asm volatile("s_waitcnt vmcnt(0)" ::: "memory");
        }
        __builtin_amdgcn_s_barrier();
        if (t + 2 < nk) stage((t + 2) % 3, (t + 2) * 64);
        int cur = t % 3;
#pragma unroll
        for (int ks = 0; ks < 2; ++ks) {
            int kk = ks * 32 + fk;
            bf16x8 af[4], bfr[4];
#pragma unroll
            for (int i = 0; i < 4; ++i)
                af[i] = *(const bf16x8*)&Ab[cur][(wm + i * 16 + fr) * 64 + (kk ^ sw)];
#pragma unroll
            for (int j = 0; j < 4; ++j)
                bfr[j] = *(const bf16x8*)&Bb[cur][(wn + j * 16 + fr) * 64 + (kk ^ sw)];
#pragma unroll
            for (int i = 0; i < 4; ++i)
#pragma unroll
                for (int j = 0; j < 4; ++j)
                    acc[i][j] = __builtin_amdgcn_mfma_f32_16x16x32_bf16(
                        af[i], bfr[j], acc[i][j], 0, 0, 0);
        }
        __builtin_amdgcn_s_barrier();     // readers done before buffer reuse
    }

#pragma unroll
    for (int i = 0; i < 4; ++i) {
#pragma unroll
        for (int j = 0; j < 4; ++j) {
            int lc = wn + j * 16 + fr;
#pragma unroll
            for (int q = 0; q < 4; ++q) {
                int lr = wm + i * 16 + fq * 4 + q;
                o1[(size_t)(bm + lr) * NTOK + bn + lc] = f2b(acc[i][j][q]);
            }
        }
    }
}

// ---------------- fused conv + x_proj, split-K, atomic accumulate ----------------
// grid (16 token-tiles, 6 K-slices of 256 d); 256 thr.
// B-tile = conv_silu(xz) computed in-register during staging (swizzle-consistent
// LDS writes); output 128 feats x 64 tokens accumulated into xdblT f32 (rows<80).
__global__ __launch_bounds__(256) void xprojf_k(const unsigned short* __restrict__ xzT,
                                                const unsigned short* __restrict__ w_xp,
                                                const float* __restrict__ cw,
                                                const float* __restrict__ cb,
                                                float* __restrict__ xdblT) {
    __shared__ __align__(16) unsigned short Ab[128 * 64];
    __shared__ __align__(16) unsigned short Bb[64 * 64];

    int tid = threadIdx.x;
    int lane = tid & 63;
    int wave = tid >> 6;
    int tok0 = blockIdx.x * 64;
    int ks = blockIdx.y;                  // 0..5
    int wm = (wave >> 1) * 64;
    int wn = (wave & 1) * 32;
    int fr = lane & 15;
    int fq = lane >> 4;
    int fk = fq * 8;
    int srow = lane >> 3;
    int scol = (lane & 7) * 8;
    int gcol = scol ^ (srow << 3);
    int sw = (fr & 7) << 3;

    int tbase = tok0 + wave * 16;         // this wave's 16 conv tokens
    bool atStart = ((tbase & 255) == 0);  // batch-sequence boundary

    f32x4 acc[4][2] = {};

    for (int t = 0; t < 4; ++t) {
        int k0 = ks * 256 + t * 64;
        // A staging (w_xp rows 0..127, swizzled global source)
#pragma unroll
        for (int c = 0; c < 4; ++c) {
            int r = wave * 32 + c * 8;
            gload16(w_xp + (size_t)(r + srow) * DINNER + k0 + gcol, &Ab[r * 64]);
        }
        // B staging: conv+SiLU in-register, write swizzled positions
        {
            int d = k0 + lane;
            const unsigned short* row = xzT + (size_t)d * NTOK + tbase;
            ushort4 z4 = {0, 0, 0, 0};
            ushort4 bl0 = atStart ? z4 : *(const ushort4*)(row - 4);
            ushort4 bl1 = *(const ushort4*)(row);
            ushort4 bl2 = *(const ushort4*)(row + 4);
            ushort4 bl3 = *(const ushort4*)(row + 8);
            ushort4 bl4 = *(const ushort4*)(row + 12);
            float4 cw4 = *(const float4*)(cw + d * 4);
            float cbv = cb[d];
            float xw[20] = {b2f(bl0.x), b2f(bl0.y), b2f(bl0.z), b2f(bl0.w),
                            b2f(bl1.x), b2f(bl1.y), b2f(bl1.z), b2f(bl1.w),
                            b2f(bl2.x), b2f(bl2.y), b2f(bl2.z), b2f(bl2.w),
                            b2f(bl3.x), b2f(bl3.y), b2f(bl3.z), b2f(bl3.w),
                            b2f(bl4.x), b2f(bl4.y), b2f(bl4.z), b2f(bl4.w)};
#pragma unroll
            for (int u = 0; u < 16; ++u) {
                float sv = cbv + cw4.x * xw[u + 1] + cw4.y * xw[u + 2] +
                           cw4.z * xw[u + 3] + cw4.w * xw[u + 4];
                float v = sv / (1.f + __expf(-sv));
                int r = wave * 16 + u;
                Bb[r * 64 + (lane ^ ((u & 7) << 3))] = f2b(v);
            }
        }
        __syncthreads();   // drains gload_lds (vmcnt) + LDS writes
#pragma unroll
        for (int kss = 0; kss < 2; ++kss) {
            int kk = kss * 32 + fk;
            bf16x8 af[4], bfr[2];
#pragma unroll
            for (int i = 0; i < 4; ++i)
                af[i] = *(const bf16x8*)&Ab[(wm + i * 16 + fr) * 64 + (kk ^ sw)];
#pragma unroll
            for (int j = 0; j < 2; ++j)
                bfr[j] = *(const bf16x8*)&Bb[(wn + j * 16 + fr) * 64 + (kk ^ sw)];
#pragma unroll
            for (int i = 0; i < 4; ++i)
#pragma unroll
                for (int j = 0; j < 2; ++j)
                    acc[i][j] = __builtin_amdgcn_mfma_f32_16x16x32_bf16(
                        af[i], bfr[j], acc[i][j], 0, 0, 0);
        }
        __syncthreads();
    }

#pragma unroll
    for (int i = 0; i < 4; ++i) {
#pragma unroll
        for (int j = 0; j < 2; ++j) {
            int lc = wn + j * 16 + fr;
#pragma unroll
            for (int q = 0; q < 4; ++q) {
                int f = wm + i * 16 + fq * 4 + q;
                if (f < 80)
                    atomicAdd(&xdblT[(size_t)f * NTOK + tok0 + lc], acc[i][j][q]);
            }
        }
    }
}

// ---------------- out_proj GEMM, BM=64, swizzled LDS + 3-buf counted vmcnt --------
__global__ __launch_bounds__(256) void opgemm_k(const unsigned short* __restrict__ A, int lda,
                                                const unsigned short* __restrict__ B, int ldb,
                                                int K,
                                                float* __restrict__ o0,
                                                unsigned short* __restrict__ o1) {
    __shared__ __align__(16) unsigned short Ab[3][64 * 64];
    __shared__ __align__(16) unsigned short Bb[3][64 * 64];

    int tid = threadIdx.x;
    int lane = tid & 63;
    int wave = tid >> 6;
    int wm = (wave >> 1) * 32;
    int wn = (wave & 1) * 32;
    int bm = blockIdx.x * 64;
    int bn = blockIdx.y * 64;
    int fr = lane & 15;
    int fq = lane >> 4;
    int fk = fq * 8;
    int srow = lane >> 3;
    int scol = (lane & 7) * 8;
    int gcol = scol ^ (srow << 3);
    int sw = (fr & 7) << 3;

    f32x4 acc[2][2] = {};

    auto stage = [&](int s, int k0) {     // 4 gload16 per wave
#pragma unroll
        for (int c = 0; c < 2; ++c) {
            int r = wave * 16 + c * 8;
            gload16(A + (size_t)(bm + r + srow) * lda + k0 + gcol, &Ab[s][r * 64]);
            gload16(B + (size_t)(bn + r + srow) * ldb + k0 + gcol, &Bb[s][r * 64]);
        }
    };

    int nk = K >> 6;
    stage(0, 0);
    stage(1, 64);

    for (int t = 0; t < nk; ++t) {
        if (t + 1 < nk) {
            asm volatile("s_waitcnt vmcnt(4)" ::: "memory");
        } else {
            asm volatile("s_waitcnt vmcnt(0)" ::: "memory");
        }
        __builtin_amdgcn_s_barrier();
        if (t + 2 < nk) stage((t + 2) % 3, (t + 2) * 64);
        int cur = t % 3;
#pragma unroll
        for (int ks = 0; ks < 2; ++ks) {
            int kk = ks * 32 + fk;
            bf16x8 af[2], bfr[2];
#pragma unroll
            for (int i = 0; i < 2; ++i)
                af[i] = *(const bf16x8*)&Ab[cur][(wm + i * 16 + fr) * 64 + (kk ^ sw)];
#pragma unroll
            for (int j = 0; j < 2; ++j)
                bfr[j] = *(const bf16x8*)&Bb[cur][(wn + j * 16 + fr) * 64 + (kk ^ sw)];
#pragma unroll
            for (int i = 0; i < 2; ++i)
#pragma unroll
                for (int j = 0; j < 2; ++j)
                    acc[i][j] = __builtin_amdgcn_mfma_f32_16x16x32_bf16(
                        af[i], bfr[j], acc[i][j], 0, 0, 0);
        }
        __builtin_amdgcn_s_barrier();
    }

#pragma unroll
    for (int i = 0; i < 2; ++i) {
#pragma unroll
        for (int j = 0; j < 2; ++j) {
            int lc = wn + j * 16 + fr;
#pragma unroll
            for (int q = 0; q < 4; ++q) {
                int lr = wm + i * 16 + fq * 4 + q;
                size_t idx = (size_t)(bm + lr) * DMODEL + bn + lc;
                float nv = o0[idx] + acc[i][j][q];
                o0[idx] = nv;
                o1[idx] = f2b(nv);
            }
        }
    }
}

// ---------------- selective scan + fused dt_proj (streamed, bounded unroll) ----------
__global__ __launch_bounds__(512) void scan_k(const unsigned short* __restrict__ xzT,
                                              const float* __restrict__ xdblT,
                                              const float* __restrict__ dpw,
                                              const float* __restrict__ dpb,
                                              const float* __restrict__ cw,
                                              const float* __restrict__ cb,
                                              const float* __restrict__ Alog,
                                              const float* __restrict__ Dsk,
                                              unsigned short* __restrict__ ybb) {
    __shared__ float dt_s[4][256];
    __shared__ float wdt_s[192];
    __shared__ float yl[4][260];
    __shared__ float cum[4][260];
    __shared__ float hL[8][4][16];
    __shared__ float Pb[8][4][16];
    __shared__ float Hin[8][4][16];

    int tid = threadIdx.x;
    int c = tid >> 6;
    int lane = tid & 63;
    int ch = lane >> 4;
    int n = lane & 15;
    int d0 = blockIdx.x * 4;
    int d = d0 + ch;
    int b = blockIdx.y;
    int tl0 = c * 32;

    if (tid < 192) wdt_s[tid] = dpw[(size_t)d0 * DTRANK + tid];
    __syncthreads();
    {
        int dd = tid >> 7;
        int tt = tid & 127;
        const float* wrow = &wdt_s[dd * DTRANK];
        const float* base = xdblT + (size_t)b * TLEN + tt;
        float a0 = 0.f, a1 = 0.f;
#pragma unroll 8
        for (int k = 0; k < DTRANK; ++k) {
            float w = wrow[k];
            a0 += w * base[(size_t)k * NTOK];
            a1 += w * base[(size_t)k * NTOK + 128];
        }
        float bias = dpb[d0 + dd];
        float v0 = a0 + bias, v1 = a1 + bias;
        v0 = (v0 > 0.f) ? v0 + log1pf(__expf(-v0)) : log1pf(__expf(v0));
        v1 = (v1 > 0.f) ? v1 + log1pf(__expf(-v1)) : log1pf(__expf(v1));
        dt_s[dd][tt] = v0;
        dt_s[dd][tt + 128] = v1;
    }
    __syncthreads();

    float a = -__expf(Alog[(size_t)d * NSTATE + n]);
    float Dv = Dsk[d];
    float w0 = cw[d * 4 + 0], w1 = cw[d * 4 + 1], w2 = cw[d * 4 + 2], w3 = cw[d * 4 + 3];
    float cbv = cb[d];
    const unsigned short* xzp = xzT + (size_t)d * NTOK + b * TLEN + tl0;
    const float* Bp = xdblT + (size_t)(DTRANK + n) * NTOK + b * TLEN + tl0;
    const float* Cp = xdblT + (size_t)(DTRANK + NSTATE + n) * NTOK + b * TLEN + tl0;

    float hm3 = 0.f, hm2 = 0.f, hm1 = 0.f;
    if (tl0 > 0) {
        ushort4 pv = *(const ushort4*)(xzp - 4);
        hm3 = b2f(pv.y); hm2 = b2f(pv.z); hm1 = b2f(pv.w);
    }

    float h = 0.f, cd = 0.f;
    for (int t8 = 0; t8 < 32; t8 += 8) {
        ushort4 xv0 = *(const ushort4*)(xzp + t8), xv1 = *(const ushort4*)(xzp + t8 + 4);
        float4 B0 = *(const float4*)(Bp + t8), B1 = *(const float4*)(Bp + t8 + 4);
        float4 C0 = *(const float4*)(Cp + t8), C1 = *(const float4*)(Cp + t8 + 4);
        float xw[11] = {hm3, hm2, hm1,
                        b2f(xv0.x), b2f(xv0.y), b2f(xv0.z), b2f(xv0.w),
                        b2f(xv1.x), b2f(xv1.y), b2f(xv1.z), b2f(xv1.w)};
        float Bs[8] = {B0.x, B0.y, B0.z, B0.w, B1.x, B1.y, B1.z, B1.w};
        float Cs[8] = {C0.x, C0.y, C0.z, C0.w, C1.x, C1.y, C1.z, C1.w};
#pragma unroll
        for (int u = 0; u < 8; ++u) {
            float sv = cbv + w0 * xw[u] + w1 * xw[u + 1] + w2 * xw[u + 2] + w3 * xw[u + 3];
            float xi = sv / (1.f + __expf(-sv));
            float dtv = dt_s[ch][tl0 + t8 + u];
            cd += dtv;
            float dA = __expf(dtv * a);
            h = dA * h + (dtv * xi) * Bs[u];
            float p = red16(h * Cs[u]);
            if (n == 0) {
                yl[ch][tl0 + t8 + u] = p + Dv * xi;
                cum[ch][tl0 + t8 + u] = cd;
            }
        }
        hm3 = xw[8]; hm2 = xw[9]; hm1 = xw[10];
    }
    hL[c][ch][n] = h;
    Pb[c][ch][n] = __expf(a * cd);
    __syncthreads();
    if (c == 0) {
        float H = 0.f;
        Hin[0][ch][n] = 0.f;
#pragma unroll
        for (int cc = 1; cc < 8; ++cc) {
            H = Pb[cc - 1][ch][n] * H + hL[cc - 1][ch][n];
            Hin[cc][ch][n] = H;
        }
    }
    __syncthreads();
    float Hv = Hin[c][ch][n];
    const unsigned short* zp = xzT + (size_t)(DINNER + d) * NTOK + b * TLEN + tl0;
    for (int t8 = 0; t8 < 32; t8 += 8) {
        float4 C0 = *(const float4*)(Cp + t8), C1 = *(const float4*)(Cp + t8 + 4);
        ushort4 zv0 = *(const ushort4*)(zp + t8), zv1 = *(const ushort4*)(zp + t8 + 4);
        float Cs[8] = {C0.x, C0.y, C0.z, C0.w, C1.x, C1.y, C1.z, C1.w};
        float zs[8] = {b2f(zv0.x), b2f(zv0.y), b2f(zv0.z), b2f(zv0.w),
                       b2f(zv1.x), b2f(zv1.y), b2f(zv1.z), b2f(zv1.w)};
#pragma unroll
        for (int u = 0; u < 8; ++u) {
            float cdt = cum[ch][tl0 + t8 + u];
            float corr = red16(Cs[u] * __expf(a * cdt) * Hv);
            if (n == 0) {
                float y = yl[ch][tl0 + t8 + u] + corr;
                float zz = zs[u];
                y *= zz / (1.f + __expf(-zz));
                yl[ch][tl0 + t8 + u] = y;
            }
        }
    }
    __syncthreads();
    if (tid < 256) {
        int t = tid;
        ushort4 o;
        o.x = f2b(yl[0][t]);
        o.y = f2b(yl[1][t]);
        o.z = f2b(yl[2][t]);
        o.w = f2b(yl[3][t]);
        *(ushort4*)(ybb + (size_t)(b * TLEN + t) * DINNER + blockIdx.x * 4) = o;
    }
}

// ---------------- RMSNorm ----------------
__global__ __launch_bounds__(256) void rmsnorm_k(const float* __restrict__ x,
                                                 const float* __restrict__ nw,
                                                 float* __restrict__ out) {
    int row = blockIdx.x;
    const float* xr = x + (size_t)row * DMODEL;
    int tid = threadIdx.x;
    float s = 0.f;
    for (int d = tid; d < DMODEL; d += 256) {
        float v = xr[d];
        s += v * v;
    }
#pragma unroll
    for (int off = 32; off >= 1; off >>= 1) s += __shfl_down(s, off);
    __shared__ float red[4];
    __shared__ float scale;
    int wid = tid >> 6, lane = tid & 63;
    if (lane == 0) red[wid] = s;
    __syncthreads();
    if (tid == 0) {
        float tot = red[0] + red[1] + red[2] + red[3];
        scale = rsqrtf(tot / (float)DMODEL + 1e-5f);
    }
    __syncthreads();
    float sc = scale;
    for (int d = tid; d < DMODEL; d += 256)
        out[(size_t)row * DMODEL + d] = xr[d] * sc * nw[d];
}

extern "C" void kernel_launch(void* const* d_in, const int* in_sizes, int n_in,
                              void* d_out, int out_size, void* d_ws, size_t ws_size,
                              hipStream_t stream) {
    const int* ids = (const int*)d_in[0];
    const float* emb = (const float*)d_in[1];
    const float* pos = (const float*)d_in[2];
    const float* ipw = (const float*)d_in[3];
    const float* cw = (const float*)d_in[4];
    const float* cb = (const float*)d_in[5];
    const float* xpw = (const float*)d_in[6];
    const float* dpw = (const float*)d_in[7];
    const float* dpb = (const float*)d_in[8];
    const float* Alog = (const float*)d_in[9];
    const float* Dsk = (const float*)d_in[10];
    const float* opw = (const float*)d_in[11];
    const float* nw = (const float*)d_in[12];

    float* x = (float*)d_ws;                             // 786432 f32
    float* xdblT = x + 786432;                           // 81920 f32
    unsigned short* xb = (unsigned short*)(xdblT + 81920);  // 786432
    unsigned short* xzT = xb + 786432;                   // 3145728
    unsigned short* ybb = xzT + 3145728;                 // 1572864
    unsigned short* w_all = ybb + 1572864;               // 4 * WL

    prep_k<<<NB_WALL + NB_E, 256, 0, stream>>>(ipw, opw, xpw, ids, emb, pos,
                                               w_all, x, xb);

    for (int l = 0; l < NLAYER; ++l) {
        const unsigned short* w_ip = w_all + (size_t)l * WL;
        const unsigned short* w_op = w_ip + S_IP;
        const unsigned short* w_xp = w_op + S_OP;
        const float* cw_l = cw + (size_t)l * DINNER * 4;
        const float* cb_l = cb + (size_t)l * DINNER;
        const float* dpw_l = dpw + (size_t)l * DINNER * DTRANK;
        const float* dpb_l = dpb + (size_t)l * DINNER;
        const float* Alog_l = Alog + (size_t)l * DINNER * NSTATE;
        const float* Dsk_l = Dsk + (size_t)l * DINNER;

        // in_proj: xzT bf16 [3072][1024] (+ zero-init xdblT for split-K)
        ipgemm_k<<<dim3(3072 / 128, NTOK / 128), 256, 0, stream>>>(w_ip, xb, xzT, xdblT);
        // fused conv + x_proj (split-K over 6 slices, atomic f32 accumulate)
        xprojf_k<<<dim3(NTOK / 64, 6), 256, 0, stream>>>(
            xzT, w_xp, cw_l, cb_l, xdblT);
        // scan (+fused dt_proj prologue, inline conv recompute)
        scan_k<<<dim3(DINNER / 4, BATCH), 512, 0, stream>>>(
            xzT, xdblT, dpw_l, dpb_l, cw_l, cb_l, Alog_l, Dsk_l, ybb);
        // out_proj: x += y @ opw^T, xb = bf16(x)
        opgemm_k<<<dim3(NTOK / 64, DMODEL / 64), 256, 0, stream>>>(
            ybb, DINNER, w_op, DINNER, DINNER, x, xb);
    }

    rmsnorm_k<<<NTOK, 256, 0, stream>>>(x, nw, (float*)d_out);
}

// Round 15
// 435.405 us; speedup vs baseline: 5.2565x; 1.0331x over previous
//
#include <hip/hip_runtime.h>
#include <math.h>

#define TLEN 256
#define BATCH 4
#define DMODEL 768
#define DINNER 1536
#define NSTATE 16
#define DTRANK 48
#define NLAYER 4
#define NTOK 1024

#define S_IP 2359296
#define S_OP 1179648
#define S_XP2 196608            /* 128 x 1536 zero-padded */
#define WL (S_IP + S_OP + S_XP2)
#define NB_W (WL / 1024)
#define NB_WALL (NB_W * NLAYER)
#define NB_E (NTOK * DMODEL / 256)

typedef __bf16 bf16x8 __attribute__((ext_vector_type(8)));
typedef float f32x4 __attribute__((ext_vector_type(4)));

__device__ inline unsigned short f2b(float f) {
    union { float f; unsigned u; } v;
    v.f = f;
    unsigned r = (v.u + 0x7fffu + ((v.u >> 16) & 1u)) >> 16;  // RNE
    return (unsigned short)r;
}
__device__ inline float b2f(unsigned short u) {
    union { unsigned u; float f; } v;
    v.u = ((unsigned)u) << 16;
    return v.f;
}

__device__ inline void gload16(const void* g, void* l) {
    __builtin_amdgcn_global_load_lds(
        (const __attribute__((address_space(1))) void*)g,
        (__attribute__((address_space(3))) void*)l, 16, 0, 0);
}

// 16-lane sum via DPP (quad xor1, xor2, then row_ror 4, 8) — no DS ops.
__device__ inline float red16(float p) {
    p += __int_as_float(__builtin_amdgcn_update_dpp(0, __float_as_int(p), 0xB1, 0xf, 0xf, true));
    p += __int_as_float(__builtin_amdgcn_update_dpp(0, __float_as_int(p), 0x4E, 0xf, 0xf, true));
    p += __int_as_float(__builtin_amdgcn_update_dpp(0, __float_as_int(p), 0x124, 0xf, 0xf, true));
    p += __int_as_float(__builtin_amdgcn_update_dpp(0, __float_as_int(p), 0x128, 0xf, 0xf, true));
    return p;
}

// ---------------- prep: all-layer weight convert + embed, one dispatch ----------------
__global__ __launch_bounds__(256) void prep_k(const float* __restrict__ ipw,
                                              const float* __restrict__ opw,
                                              const float* __restrict__ xpw,
                                              const int* __restrict__ ids,
                                              const float* __restrict__ emb,
                                              const float* __restrict__ pos,
                                              unsigned short* __restrict__ w_all,
                                              float* __restrict__ x,
                                              unsigned short* __restrict__ xb) {
    int bid = blockIdx.x;
    int tid = threadIdx.x;
    if (bid >= NB_WALL) {  // embed
        int idx = (bid - NB_WALL) * 256 + tid;
        int d = idx % DMODEL;
        int bt = idx / DMODEL;
        int t = bt % TLEN;
        float v = emb[(size_t)ids[bt] * DMODEL + d] + pos[t * DMODEL + d];
        x[idx] = v;
        xb[idx] = f2b(v);
        return;
    }
    int l = bid / NB_W;
    int i4 = ((bid % NB_W) * 256 + tid) * 4;
    unsigned short* wl = w_all + (size_t)l * WL;
    if (i4 < S_IP) {
        float4 v = *(const float4*)(ipw + (size_t)l * S_IP + i4);
        ushort4 o; o.x = f2b(v.x); o.y = f2b(v.y); o.z = f2b(v.z); o.w = f2b(v.w);
        *(ushort4*)(wl + i4) = o;
    } else if (i4 < S_IP + S_OP) {
        int i = i4 - S_IP;
        float4 v = *(const float4*)(opw + (size_t)l * S_OP + i);
        ushort4 o; o.x = f2b(v.x); o.y = f2b(v.y); o.z = f2b(v.z); o.w = f2b(v.w);
        *(ushort4*)(wl + S_IP + i) = o;
    } else {
        int i = i4 - S_IP - S_OP;
        int r = i / 1536, k = i % 1536;
        ushort4 o = {0, 0, 0, 0};
        if (r < 80) {
            float4 v = *(const float4*)(xpw + (size_t)l * (80 * 1536) + (size_t)r * 1536 + k);
            o.x = f2b(v.x); o.y = f2b(v.y); o.z = f2b(v.z); o.w = f2b(v.w);
        }
        *(ushort4*)(wl + S_IP + S_OP + i) = o;
    }
}

// ---------------- in_proj GEMM: 128x64 tile (2 blocks/CU), swizzled + counted vmcnt --
// Also zero-inits xdblT for the split-K x_proj that follows.
__global__ __launch_bounds__(256) void ipgemm_k(const unsigned short* __restrict__ A,
                                                const unsigned short* __restrict__ B,
                                                unsigned short* __restrict__ o1,
                                                float* __restrict__ xdblT) {
    __shared__ __align__(16) unsigned short Ab[3][128 * 64];
    __shared__ __align__(16) unsigned short Bb[3][64 * 64];

    int tid = threadIdx.x;
    {   // zero xdblT (81920 f32 = 40960 float2) across 384 blocks
        int unit = (blockIdx.x * gridDim.y + blockIdx.y) * 256 + tid;
        if (unit < 40960) {
            float2 z = {0.f, 0.f};
            *(float2*)(xdblT + unit * 2) = z;
        }
    }
    int lane = tid & 63;
    int wave = tid >> 6;
    int wm = (wave >> 1) * 64;            // 0,64
    int wn = (wave & 1) * 32;             // 0,32
    int bm = blockIdx.x * 128;
    int bn = blockIdx.y * 64;
    int fr = lane & 15;
    int fq = lane >> 4;
    int fk = fq * 8;
    int srow = lane >> 3;                 // 0..7
    int scol = (lane & 7) * 8;            // chunk*8 elems
    int gcol = scol ^ (srow << 3);        // pre-swizzled global chunk (rule #21)
    int sw = (fr & 7) << 3;               // read-side swizzle

    f32x4 acc[4][2] = {};

    auto stage = [&](int s, int k0) {     // 6 gload16 per wave
#pragma unroll
        for (int c = 0; c < 4; ++c) {
            int r = wave * 32 + c * 8;
            gload16(A + (size_t)(bm + r + srow) * DMODEL + k0 + gcol, &Ab[s][r * 64]);
        }
#pragma unroll
        for (int c = 0; c < 2; ++c) {
            int r = wave * 16 + c * 8;
            gload16(B + (size_t)(bn + r + srow) * DMODEL + k0 + gcol, &Bb[s][r * 64]);
        }
    };

    const int nk = DMODEL / 64;  // 12
    stage(0, 0);
    stage(1, 64);

    for (int t = 0; t < nk; ++t) {
        if (t + 1 < nk) {
            asm volatile("s_waitcnt vmcnt(6)" ::: "memory");   // stage t landed
        } else {
            asm volatile("s_waitcnt vmcnt(0)" ::: "memory");
        }
        __builtin_amdgcn_s_barrier();
        if (t + 2 < nk) stage((t + 2) % 3, (t + 2) * 64);
        int cur = t % 3;
#pragma unroll
        for (int ks = 0; ks < 2; ++ks) {
            int kk = ks * 32 + fk;
            bf16x8 af[4], bfr[2];
#pragma unroll
            for (int i = 0; i < 4; ++i)
                af[i] = *(const bf16x8*)&Ab[cur][(wm + i * 16 + fr) * 64 + (kk ^ sw)];
#pragma unroll
            for (int j = 0; j < 2; ++j)
                bfr[j] = *(const bf16x8*)&Bb[cur][(wn + j * 16 + fr) * 64 + (kk ^ sw)];
#pragma unroll
            for (int i = 0; i < 4; ++i)
#pragma unroll
                for (int j = 0; j < 2; ++j)
                    acc[i][j] = __builtin_amdgcn_mfma_f32_16x16x32_bf16(
                        af[i], bfr[j], acc[i][j], 0, 0, 0);
        }
        __builtin_amdgcn_s_barrier();     // readers done before buffer reuse
    }

#pragma unroll
    for (int i = 0; i < 4; ++i) {
#pragma unroll
        for (int j = 0; j < 2; ++j) {
            int lc = wn + j * 16 + fr;
#pragma unroll
            for (int q = 0; q < 4; ++q) {
                int lr = wm + i * 16 + fq * 4 + q;
                o1[(size_t)(bm + lr) * NTOK + bn + lc] = f2b(acc[i][j][q]);
            }
        }
    }
}

// ---------------- fused conv + x_proj, split-K (12 slices), atomic accumulate -------
// grid (16 token-tiles, 12 K-slices of 128 d); 256 thr.
__global__ __launch_bounds__(256) void xprojf_k(const unsigned short* __restrict__ xzT,
                                                const unsigned short* __restrict__ w_xp,
                                                const float* __restrict__ cw,
                                                const float* __restrict__ cb,
                                                float* __restrict__ xdblT) {
    __shared__ __align__(16) unsigned short Ab[128 * 64];
    __shared__ __align__(16) unsigned short Bb[64 * 64];

    int tid = threadIdx.x;
    int lane = tid & 63;
    int wave = tid >> 6;
    int tok0 = blockIdx.x * 64;
    int ks = blockIdx.y;                  // 0..11
    int wm = (wave >> 1) * 64;
    int wn = (wave & 1) * 32;
    int fr = lane & 15;
    int fq = lane >> 4;
    int fk = fq * 8;
    int srow = lane >> 3;
    int scol = (lane & 7) * 8;
    int gcol = scol ^ (srow << 3);
    int sw = (fr & 7) << 3;

    int tbase = tok0 + wave * 16;         // this wave's 16 conv tokens
    bool atStart = ((tbase & 255) == 0);  // batch-sequence boundary

    f32x4 acc[4][2] = {};

    for (int t = 0; t < 2; ++t) {
        int k0 = ks * 128 + t * 64;
        // A staging (w_xp rows 0..127, swizzled global source)
#pragma unroll
        for (int c = 0; c < 4; ++c) {
            int r = wave * 32 + c * 8;
            gload16(w_xp + (size_t)(r + srow) * DINNER + k0 + gcol, &Ab[r * 64]);
        }
        // B staging: conv+SiLU in-register, write swizzled positions
        {
            int d = k0 + lane;
            const unsigned short* row = xzT + (size_t)d * NTOK + tbase;
            ushort4 z4 = {0, 0, 0, 0};
            ushort4 bl0 = atStart ? z4 : *(const ushort4*)(row - 4);
            ushort4 bl1 = *(const ushort4*)(row);
            ushort4 bl2 = *(const ushort4*)(row + 4);
            ushort4 bl3 = *(const ushort4*)(row + 8);
            ushort4 bl4 = *(const ushort4*)(row + 12);
            float4 cw4 = *(const float4*)(cw + d * 4);
            float cbv = cb[d];
            float xw[20] = {b2f(bl0.x), b2f(bl0.y), b2f(bl0.z), b2f(bl0.w),
                            b2f(bl1.x), b2f(bl1.y), b2f(bl1.z), b2f(bl1.w),
                            b2f(bl2.x), b2f(bl2.y), b2f(bl2.z), b2f(bl2.w),
                            b2f(bl3.x), b2f(bl3.y), b2f(bl3.z), b2f(bl3.w),
                            b2f(bl4.x), b2f(bl4.y), b2f(bl4.z), b2f(bl4.w)};
#pragma unroll
            for (int u = 0; u < 16; ++u) {
                float sv = cbv + cw4.x * xw[u + 1] + cw4.y * xw[u + 2] +
                           cw4.z * xw[u + 3] + cw4.w * xw[u + 4];
                float v = sv / (1.f + __expf(-sv));
                int r = wave * 16 + u;
                Bb[r * 64 + (lane ^ ((u & 7) << 3))] = f2b(v);
            }
        }
        __syncthreads();   // drains gload_lds (vmcnt) + LDS writes
#pragma unroll
        for (int kss = 0; kss < 2; ++kss) {
            int kk = kss * 32 + fk;
            bf16x8 af[4], bfr[2];
#pragma unroll
            for (int i = 0; i < 4; ++i)
                af[i] = *(const bf16x8*)&Ab[(wm + i * 16 + fr) * 64 + (kk ^ sw)];
#pragma unroll
            for (int j = 0; j < 2; ++j)
                bfr[j] = *(const bf16x8*)&Bb[(wn + j * 16 + fr) * 64 + (kk ^ sw)];
#pragma unroll
            for (int i = 0; i < 4; ++i)
#pragma unroll
                for (int j = 0; j < 2; ++j)
                    acc[i][j] = __builtin_amdgcn_mfma_f32_16x16x32_bf16(
                        af[i], bfr[j], acc[i][j], 0, 0, 0);
        }
        __syncthreads();
    }

#pragma unroll
    for (int i = 0; i < 4; ++i) {
#pragma unroll
        for (int j = 0; j < 2; ++j) {
            int lc = wn + j * 16 + fr;
#pragma unroll
            for (int q = 0; q < 4; ++q) {
                int f = wm + i * 16 + fq * 4 + q;
                if (f < 80)
                    atomicAdd(&xdblT[(size_t)f * NTOK + tok0 + lc], acc[i][j][q]);
            }
        }
    }
}

// ---------------- out_proj GEMM, BM=64, swizzled LDS + 3-buf counted vmcnt --------
__global__ __launch_bounds__(256) void opgemm_k(const unsigned short* __restrict__ A, int lda,
                                                const unsigned short* __restrict__ B, int ldb,
                                                int K,
                                                float* __restrict__ o0,
                                                unsigned short* __restrict__ o1) {
    __shared__ __align__(16) unsigned short Ab[3][64 * 64];
    __shared__ __align__(16) unsigned short Bb[3][64 * 64];

    int tid = threadIdx.x;
    int lane = tid & 63;
    int wave = tid >> 6;
    int wm = (wave >> 1) * 32;
    int wn = (wave & 1) * 32;
    int bm = blockIdx.x * 64;
    int bn = blockIdx.y * 64;
    int fr = lane & 15;
    int fq = lane >> 4;
    int fk = fq * 8;
    int srow = lane >> 3;
    int scol = (lane & 7) * 8;
    int gcol = scol ^ (srow << 3);
    int sw = (fr & 7) << 3;

    f32x4 acc[2][2] = {};

    auto stage = [&](int s, int k0) {     // 4 gload16 per wave
#pragma unroll
        for (int c = 0; c < 2; ++c) {
            int r = wave * 16 + c * 8;
            gload16(A + (size_t)(bm + r + srow) * lda + k0 + gcol, &Ab[s][r * 64]);
            gload16(B + (size_t)(bn + r + srow) * ldb + k0 + gcol, &Bb[s][r * 64]);
        }
    };

    int nk = K >> 6;
    stage(0, 0);
    stage(1, 64);

    for (int t = 0; t < nk; ++t) {
        if (t + 1 < nk) {
            asm volatile("s_waitcnt vmcnt(4)" ::: "memory");
        } else {
            asm volatile("s_waitcnt vmcnt(0)" ::: "memory");
        }
        __builtin_amdgcn_s_barrier();
        if (t + 2 < nk) stage((t + 2) % 3, (t + 2) * 64);
        int cur = t % 3;
#pragma unroll
        for (int ks = 0; ks < 2; ++ks) {
            int kk = ks * 32 + fk;
            bf16x8 af[2], bfr[2];
#pragma unroll
            for (int i = 0; i < 2; ++i)
                af[i] = *(const bf16x8*)&Ab[cur][(wm + i * 16 + fr) * 64 + (kk ^ sw)];
#pragma unroll
            for (int j = 0; j < 2; ++j)
                bfr[j] = *(const bf16x8*)&Bb[cur][(wn + j * 16 + fr) * 64 + (kk ^ sw)];
#pragma unroll
            for (int i = 0; i < 2; ++i)
#pragma unroll
                for (int j = 0; j < 2; ++j)
                    acc[i][j] = __builtin_amdgcn_mfma_f32_16x16x32_bf16(
                        af[i], bfr[j], acc[i][j], 0, 0, 0);
        }
        __builtin_amdgcn_s_barrier();
    }

#pragma unroll
    for (int i = 0; i < 2; ++i) {
#pragma unroll
        for (int j = 0; j < 2; ++j) {
            int lc = wn + j * 16 + fr;
#pragma unroll
            for (int q = 0; q < 4; ++q) {
                int lr = wm + i * 16 + fq * 4 + q;
                size_t idx = (size_t)(bm + lr) * DMODEL + bn + lc;
                float nv = o0[idx] + acc[i][j][q];
                o0[idx] = nv;
                o1[idx] = f2b(nv);
            }
        }
    }
}

// ---------------- selective scan + fused dt_proj (streamed, bounded unroll) ----------
__global__ __launch_bounds__(512) void scan_k(const unsigned short* __restrict__ xzT,
                                              const float* __restrict__ xdblT,
                                              const float* __restrict__ dpw,
                                              const float* __restrict__ dpb,
                                              const float* __restrict__ cw,
                                              const float* __restrict__ cb,
                                              const float* __restrict__ Alog,
                                              const float* __restrict__ Dsk,
                                              unsigned short* __restrict__ ybb) {
    __shared__ float dt_s[4][256];
    __shared__ float wdt_s[192];
    __shared__ float yl[4][260];
    __shared__ float cum[4][260];
    __shared__ float hL[8][4][16];
    __shared__ float Pb[8][4][16];
    __shared__ float Hin[8][4][16];

    int tid = threadIdx.x;
    int c = tid >> 6;
    int lane = tid & 63;
    int ch = lane >> 4;
    int n = lane & 15;
    int d0 = blockIdx.x * 4;
    int d = d0 + ch;
    int b = blockIdx.y;
    int tl0 = c * 32;

    if (tid < 192) wdt_s[tid] = dpw[(size_t)d0 * DTRANK + tid];
    __syncthreads();
    {
        int dd = tid >> 7;
        int tt = tid & 127;
        const float* wrow = &wdt_s[dd * DTRANK];
        const float* base = xdblT + (size_t)b * TLEN + tt;
        float a0 = 0.f, a1 = 0.f;
#pragma unroll 8
        for (int k = 0; k < DTRANK; ++k) {
            float w = wrow[k];
            a0 += w * base[(size_t)k * NTOK];
            a1 += w * base[(size_t)k * NTOK + 128];
        }
        float bias = dpb[d0 + dd];
        float v0 = a0 + bias, v1 = a1 + bias;
        v0 = (v0 > 0.f) ? v0 + log1pf(__expf(-v0)) : log1pf(__expf(v0));
        v1 = (v1 > 0.f) ? v1 + log1pf(__expf(-v1)) : log1pf(__expf(v1));
        dt_s[dd][tt] = v0;
        dt_s[dd][tt + 128] = v1;
    }
    __syncthreads();

    float a = -__expf(Alog[(size_t)d * NSTATE + n]);
    float Dv = Dsk[d];
    float w0 = cw[d * 4 + 0], w1 = cw[d * 4 + 1], w2 = cw[d * 4 + 2], w3 = cw[d * 4 + 3];
    float cbv = cb[d];
    const unsigned short* xzp = xzT + (size_t)d * NTOK + b * TLEN + tl0;
    const float* Bp = xdblT + (size_t)(DTRANK + n) * NTOK + b * TLEN + tl0;
    const float* Cp = xdblT + (size_t)(DTRANK + NSTATE + n) * NTOK + b * TLEN + tl0;

    float hm3 = 0.f, hm2 = 0.f, hm1 = 0.f;
    if (tl0 > 0) {
        ushort4 pv = *(const ushort4*)(xzp - 4);
        hm3 = b2f(pv.y); hm2 = b2f(pv.z); hm1 = b2f(pv.w);
    }

    float h = 0.f, cd = 0.f;
    for (int t8 = 0; t8 < 32; t8 += 8) {
        ushort4 xv0 = *(const ushort4*)(xzp + t8), xv1 = *(const ushort4*)(xzp + t8 + 4);
        float4 B0 = *(const float4*)(Bp + t8), B1 = *(const float4*)(Bp + t8 + 4);
        float4 C0 = *(const float4*)(Cp + t8), C1 = *(const float4*)(Cp + t8 + 4);
        float xw[11] = {hm3, hm2, hm1,
                        b2f(xv0.x), b2f(xv0.y), b2f(xv0.z), b2f(xv0.w),
                        b2f(xv1.x), b2f(xv1.y), b2f(xv1.z), b2f(xv1.w)};
        float Bs[8] = {B0.x, B0.y, B0.z, B0.w, B1.x, B1.y, B1.z, B1.w};
        float Cs[8] = {C0.x, C0.y, C0.z, C0.w, C1.x, C1.y, C1.z, C1.w};
#pragma unroll
        for (int u = 0; u < 8; ++u) {
            float sv = cbv + w0 * xw[u] + w1 * xw[u + 1] + w2 * xw[u + 2] + w3 * xw[u + 3];
            float xi = sv / (1.f + __expf(-sv));
            float dtv = dt_s[ch][tl0 + t8 + u];
            cd += dtv;
            float dA = __expf(dtv * a);
            h = dA * h + (dtv * xi) * Bs[u];
            float p = red16(h * Cs[u]);
            if (n == 0) {
                yl[ch][tl0 + t8 + u] = p + Dv * xi;
                cum[ch][tl0 + t8 + u] = cd;
            }
        }
        hm3 = xw[8]; hm2 = xw[9]; hm1 = xw[10];
    }
    hL[c][ch][n] = h;
    Pb[c][ch][n] = __expf(a * cd);
    __syncthreads();
    if (c == 0) {
        float H = 0.f;
        Hin[0][ch][n] = 0.f;
#pragma unroll
        for (int cc = 1; cc < 8; ++cc) {
            H = Pb[cc - 1][ch][n] * H + hL[cc - 1][ch][n];
            Hin[cc][ch][n] = H;
        }
    }
    __syncthreads();
    float Hv = Hin[c][ch][n];
    const unsigned short* zp = xzT + (size_t)(DINNER + d) * NTOK + b * TLEN + tl0;
    for (int t8 = 0; t8 < 32; t8 += 8) {
        float4 C0 = *(const float4*)(Cp + t8), C1 = *(const float4*)(Cp + t8 + 4);
        ushort4 zv0 = *(const ushort4*)(zp + t8), zv1 = *(const ushort4*)(zp + t8 + 4);
        float Cs[8] = {C0.x, C0.y, C0.z, C0.w, C1.x, C1.y, C1.z, C1.w};
        float zs[8] = {b2f(zv0.x), b2f(zv0.y), b2f(zv0.z), b2f(zv0.w),
                       b2f(zv1.x), b2f(zv1.y), b2f(zv1.z), b2f(zv1.w)};
#pragma unroll
        for (int u = 0; u < 8; ++u) {
            float cdt = cum[ch][tl0 + t8 + u];
            float corr = red16(Cs[u] * __expf(a * cdt) * Hv);
            if (n == 0) {
                float y = yl[ch][tl0 + t8 + u] + corr;
                float zz = zs[u];
                y *= zz / (1.f + __expf(-zz));
                yl[ch][tl0 + t8 + u] = y;
            }
        }
    }
    __syncthreads();
    if (tid < 256) {
        int t = tid;
        ushort4 o;
        o.x = f2b(yl[0][t]);
        o.y = f2b(yl[1][t]);
        o.z = f2b(yl[2][t]);
        o.w = f2b(yl[3][t]);
        *(ushort4*)(ybb + (size_t)(b * TLEN + t) * DINNER + blockIdx.x * 4) = o;
    }
}

// ---------------- RMSNorm ----------------
__global__ __launch_bounds__(256) void rmsnorm_k(const float* __restrict__ x,
                                                 const float* __restrict__ nw,
                                                 float* __restrict__ out) {
    int row = blockIdx.x;
    const float* xr = x + (size_t)row * DMODEL;
    int tid = threadIdx.x;
    float s = 0.f;
    for (int d = tid; d < DMODEL; d += 256) {
        float v = xr[d];
        s += v * v;
    }
#pragma unroll
    for (int off = 32; off >= 1; off >>= 1) s += __shfl_down(s, off);
    __shared__ float red[4];
    __shared__ float scale;
    int wid = tid >> 6, lane = tid & 63;
    if (lane == 0) red[wid] = s;
    __syncthreads();
    if (tid == 0) {
        float tot = red[0] + red[1] + red[2] + red[3];
        scale = rsqrtf(tot / (float)DMODEL + 1e-5f);
    }
    __syncthreads();
    float sc = scale;
    for (int d = tid; d < DMODEL; d += 256)
        out[(size_t)row * DMODEL + d] = xr[d] * sc * nw[d];
}

extern "C" void kernel_launch(void* const* d_in, const int* in_sizes, int n_in,
                              void* d_out, int out_size, void* d_ws, size_t ws_size,
                              hipStream_t stream) {
    const int* ids = (const int*)d_in[0];
    const float* emb = (const float*)d_in[1];
    const float* pos = (const float*)d_in[2];
    const float* ipw = (const float*)d_in[3];
    const float* cw = (const float*)d_in[4];
    const float* cb = (const float*)d_in[5];
    const float* xpw = (const float*)d_in[6];
    const float* dpw = (const float*)d_in[7];
    const float* dpb = (const float*)d_in[8];
    const float* Alog = (const float*)d_in[9];
    const float* Dsk = (const float*)d_in[10];
    const float* opw = (const float*)d_in[11];
    const float* nw = (const float*)d_in[12];

    float* x = (float*)d_ws;                             // 786432 f32
    float* xdblT = x + 786432;                           // 81920 f32
    unsigned short* xb = (unsigned short*)(xdblT + 81920);  // 786432
    unsigned short* xzT = xb + 786432;                   // 3145728
    unsigned short* ybb = xzT + 3145728;                 // 1572864
    unsigned short* w_all = ybb + 1572864;               // 4 * WL

    prep_k<<<NB_WALL + NB_E, 256, 0, stream>>>(ipw, opw, xpw, ids, emb, pos,
                                               w_all, x, xb);

    for (int l = 0; l < NLAYER; ++l) {
        const unsigned short* w_ip = w_all + (size_t)l * WL;
        const unsigned short* w_op = w_ip + S_IP;
        const unsigned short* w_xp = w_op + S_OP;
        const float* cw_l = cw + (size_t)l * DINNER * 4;
        const float* cb_l = cb + (size_t)l * DINNER;
        const float* dpw_l = dpw + (size_t)l * DINNER * DTRANK;
        const float* dpb_l = dpb + (size_t)l * DINNER;
        const float* Alog_l = Alog + (size_t)l * DINNER * NSTATE;
        const float* Dsk_l = Dsk + (size_t)l * DINNER;

        // in_proj: xzT bf16 [3072][1024], 128x64 tiles (384 blocks, 2/CU)
        ipgemm_k<<<dim3(3072 / 128, NTOK / 64), 256, 0, stream>>>(w_ip, xb, xzT, xdblT);
        // fused conv + x_proj (split-K over 12 slices, atomic f32 accumulate)
        xprojf_k<<<dim3(NTOK / 64, 12), 256, 0, stream>>>(
            xzT, w_xp, cw_l, cb_l, xdblT);
        // scan (+fused dt_proj prologue, inline conv recompute)
        scan_k<<<dim3(DINNER / 4, BATCH), 512, 0, stream>>>(
            xzT, xdblT, dpw_l, dpb_l, cw_l, cb_l, Alog_l, Dsk_l, ybb);
        // out_proj: x += y @ opw^T, xb = bf16(x)
        opgemm_k<<<dim3(NTOK / 64, DMODEL / 64), 256, 0, stream>>>(
            ybb, DINNER, w_op, DINNER, DINNER, x, xb);
    }

    rmsnorm_k<<<NTOK, 256, 0, stream>>>(x, nw, (float*)d_out);
}